// Round 18
// baseline (1297.654 us; speedup 1.0000x reference)
//
#include <hip/hip_runtime.h>
#include <hip/hip_bf16.h>

#define N_NODES 20000
#define N_EDGES 320000
#define T_STEPS 64
#define F_IN    16
#define HGd     128
#define HTd     256
#define INVN    (1.0f/20000.0f)
#define NT64     313            // sage2 tiles (64 nodes)
#define S1T      79
#define NG64     313
#define QSCALE   64.0f
#define INVQ     (1.0f/64.0f)
#define QX       32.0f
#define INVQX    (1.0f/32.0f)
#define S_Q8     ((size_t)(N_NODES + 1) * HGd)   // fp8 slice stride incl. zero row

typedef __attribute__((ext_vector_type(8))) short short8;
typedef __attribute__((ext_vector_type(4))) float f32x4;
typedef __attribute__((ext_vector_type(2))) float f32x2;
typedef __attribute__((ext_vector_type(2))) _Float16 half2t;

static __device__ __forceinline__ ushort f2bf(float f) {
    __hip_bfloat16 b = __float2bfloat16(f);
    return *reinterpret_cast<ushort*>(&b);
}
static __device__ __forceinline__ half2t u2h(uint u) {
    half2t h; __builtin_memcpy(&h, &u, 4); return h;
}
static __device__ __forceinline__ uint packf16(float a, float b) {
    auto h = __builtin_amdgcn_cvt_pkrtz(a, b);
    uint u; __builtin_memcpy(&u, &h, 4); return u;
}

// ---------------- init ----------------
__global__ void k_zero(int* __restrict__ deg, float* __restrict__ HgP,
                       int* __restrict__ jobc, int* __restrict__ bins,
                       uint* __restrict__ h1q, int tch) {
    int i = blockIdx.x * blockDim.x + threadIdx.x;
    if (i < N_NODES) deg[i] = 0;
    if (i < T_STEPS * 8 * HGd) HgP[i] = 0.0f;
    if (i < 1024) jobc[i] = 0;
    if (i < 256) bins[i] = 0;
    if (i < tch * 32) {          // zero row N_NODES of each fp8 slice (32 uints)
        int sl = i >> 5, j = i & 31;
        h1q[sl * (S_Q8 / 4) + (size_t)N_NODES * (HGd / 4) + j] = 0u;
    }
}

__global__ void k_degree(const int* __restrict__ ei, int* __restrict__ deg) {
    int e = blockIdx.x * blockDim.x + threadIdx.x;
    if (e < N_EDGES) atomicAdd(&deg[ei[N_EDGES + e]], 1);
}

__global__ __launch_bounds__(1024) void k_scan(const int* __restrict__ deg,
        int* __restrict__ rp, int* __restrict__ cursor, float* __restrict__ invd) {
    __shared__ int sh[1024];
    __shared__ int carry_s;
    int tid = threadIdx.x;
    if (tid == 0) { carry_s = 0; rp[0] = 0; }
    __syncthreads();
    for (int base = 0; base < N_NODES; base += 1024) {
        int i = base + tid;
        int v = (i < N_NODES) ? deg[i] : 0;
        sh[tid] = v;
        __syncthreads();
        for (int off = 1; off < 1024; off <<= 1) {
            int t = (tid >= off) ? sh[tid - off] : 0;
            __syncthreads();
            sh[tid] += t;
            __syncthreads();
        }
        int inc = sh[tid] + carry_s;
        if (i < N_NODES) {
            rp[i + 1] = inc;
            cursor[i] = inc - v;
            invd[i] = (v > 0) ? (1.0f / (float)v) : 0.0f;
        }
        __syncthreads();
        if (tid == 1023) carry_s = inc;
        __syncthreads();
    }
}

__global__ void k_fill(const int* __restrict__ ei, int* __restrict__ cursor,
                       int* __restrict__ csr) {
    int e = blockIdx.x * blockDim.x + threadIdx.x;
    if (e < N_EDGES) {
        int d = ei[N_EDGES + e];
        int p = atomicAdd(&cursor[d], 1);
        csr[p] = ei[e];
    }
}

// ---------------- degree-sort permutation ----------------
__global__ void k_hist(const int* __restrict__ deg, int* __restrict__ bins) {
    int i = blockIdx.x * blockDim.x + threadIdx.x;
    if (i < N_NODES) atomicAdd(&bins[min(deg[i], 255)], 1);
}

__global__ __launch_bounds__(256) void k_binscan(const int* __restrict__ bins,
        int* __restrict__ bincur, int* __restrict__ nodebefore,
        int* __restrict__ edgebefore, int* __restrict__ edgebp, int* __restrict__ rp2p) {
    __shared__ int sh[256], she[256], shp[256];
    int tid = threadIdx.x;
    int b = bins[tid];
    int dp = (tid + 7) & ~7;
    sh[tid] = b;
    she[tid] = b * tid;
    shp[tid] = b * dp;
    __syncthreads();
    for (int off = 1; off < 256; off <<= 1) {
        int v = (tid >= off) ? sh[tid - off] : 0;
        int ve = (tid >= off) ? she[tid - off] : 0;
        int vp = (tid >= off) ? shp[tid - off] : 0;
        __syncthreads();
        sh[tid] += v; she[tid] += ve; shp[tid] += vp;
        __syncthreads();
    }
    bincur[tid] = sh[tid] - b;
    nodebefore[tid] = sh[tid] - b;
    edgebefore[tid] = she[tid] - b * tid;
    edgebp[tid] = shp[tid] - b * dp;
    if (tid == 255) rp2p[N_NODES] = shp[255];
}

__global__ void k_perm(const int* __restrict__ deg, int* __restrict__ bincur,
                       const int* __restrict__ nodebefore, const int* __restrict__ edgebefore,
                       const int* __restrict__ edgebp, const float* __restrict__ invd,
                       int* __restrict__ perm, int* __restrict__ pos,
                       int* __restrict__ rp2, float* __restrict__ invd2,
                       int* __restrict__ degs2, int* __restrict__ rp2p) {
    int i = blockIdx.x * blockDim.x + threadIdx.x;
    if (i < N_NODES) {
        int d = min(deg[i], 255);
        int p = atomicAdd(&bincur[d], 1);
        int rank = p - nodebefore[d];
        perm[p] = i;
        pos[i] = p;
        rp2[p] = edgebefore[d] + rank * d;
        rp2p[p] = edgebp[d] + rank * ((d + 7) & ~7);
        invd2[p] = invd[i];
        degs2[p] = deg[i];
        if (i == 0) rp2[N_NODES] = N_EDGES;
    }
}

// per-64-group transposed edge-list bases (sage1)
__global__ __launch_bounds__(512) void k_tb(const int* __restrict__ rp2, int* __restrict__ tb) {
    __shared__ int sh[512];
    int t = threadIdx.x;
    int md = 0;
    if (t < NG64 && t * 64 < N_NODES) {
        int last = min((t + 1) * 64, N_NODES) - 1;
        md = rp2[last + 1] - rp2[last];
    }
    sh[t] = 64 * md;
    __syncthreads();
    for (int off = 1; off < 512; off <<= 1) {
        int v = (t >= off) ? sh[t - off] : 0;
        __syncthreads();
        sh[t] += v;
        __syncthreads();
    }
    tb[t + 1] = sh[t];
    if (t == 0) tb[0] = 0;
}

// edge-parallel scatter into csr3 (sage1) and csr2p (sage2 padded)
__global__ void k_ecopy(const int* __restrict__ rp, const int* __restrict__ pos,
                        const int* __restrict__ rp2p, const int* __restrict__ tb,
                        const int* __restrict__ csr,
                        int* __restrict__ csr3, int* __restrict__ csr2p) {
    int e = blockIdx.x * blockDim.x + threadIdx.x;
    if (e < N_EDGES) {
        int lo = 0, hi = N_NODES - 1;
#pragma unroll
        for (int it = 0; it < 15; ++it) {
            int mid = (lo + hi + 1) >> 1;
            if (rp[mid] <= e) lo = mid; else hi = mid - 1;
        }
        int i = lo;
        int j = e - rp[i];
        int p = pos[i];
        int v = csr[e];
        csr3[tb[p >> 6] + j * 64 + (p & 63)] = v;
        csr2p[rp2p[p] + j] = v;
    }
}

__global__ void k_pad(const int* __restrict__ rp, const int* __restrict__ pos,
                      const int* __restrict__ rp2p, int* __restrict__ csr2p) {
    int i = blockIdx.x * blockDim.x + threadIdx.x;
    if (i < N_NODES) {
        int d = rp[i + 1] - rp[i];
        int dp = (d + 7) & ~7;
        int o = rp2p[pos[i]];
        for (int k = d; k < dp; ++k) csr2p[o + k] = N_NODES;   // fp8 zero row
    }
}

// ---------------- x_seq fp32 -> fp8 (x32) ----------------
__global__ void k_qx(const float* __restrict__ xs, int* __restrict__ x8, int n4) {
    int i = blockIdx.x * blockDim.x + threadIdx.x;
    if (i < n4) {
        float4 v = reinterpret_cast<const float4*>(xs)[i];
        int q8 = __builtin_amdgcn_cvt_pk_fp8_f32(v.x * QX, v.y * QX, 0, false);
        q8 = __builtin_amdgcn_cvt_pk_fp8_f32(v.z * QX, v.w * QX, q8, true);
        x8[i] = q8;
    }
}

// ---------------- weight prep ----------------
__global__ void k_prepw(const float* __restrict__ W1l, const float* __restrict__ W1r,
                        const float* __restrict__ W2l, const float* __restrict__ W2r,
                        const float* __restrict__ W_ih, const float* __restrict__ W_hh,
                        ushort* __restrict__ W1T2, ushort* __restrict__ WT2,
                        float* __restrict__ WihT, uint* __restrict__ W_hhq) {
    int i = blockIdx.x * blockDim.x + threadIdx.x;
    const int n1 = 128 * 32, n2 = 128 * 256, n3 = 128 * 768, n4 = 128 * 768;
    if (i < n1) {
        int o = i >> 5, k = i & 31;
        float v = (k < 16) ? W1l[o * 16 + k] : W1r[o * 16 + (k - 16)];
        W1T2[i] = f2bf(v);
    } else if (i < n1 + n2) {
        int j = i - n1; int o = j >> 8, k = j & 255;
        float v = (k < 128) ? W2l[o * 128 + k] : W2r[o * 128 + (k - 128)];
        WT2[j] = f2bf(v);
    } else if (i < n1 + n2 + n3) {
        int j = i - n1 - n2; int k = j / 768, g = j % 768;
        WihT[j] = W_ih[g * 128 + k];
    } else if (i < n1 + n2 + n3 + n4) {
        int j = i - n1 - n2 - n3; int dw = j / 768, row = j % 768;
        float a = W_hh[(size_t)row * HTd + 2 * dw];
        float b = W_hh[(size_t)row * HTd + 2 * dw + 1];
        W_hhq[j] = packf16(a, b);
    }
}

// ---------------- SAGE layer 1 (lane-per-node fp8 gather, unroll-2, + bf16 MFMA) ----------------
__global__ __launch_bounds__(256) void k_sage1(
        const char* __restrict__ x8_, const int* __restrict__ tb,
        const int* __restrict__ csr3, const int* __restrict__ degs2,
        const float* __restrict__ invd2,
        const ushort* __restrict__ W1T2, const float* __restrict__ b1l,
        const int* __restrict__ perm, uchar1* __restrict__ h1q_,
        int* __restrict__ jobc, int C) {
    __shared__ ushort u[256 * 40];
    __shared__ int pnode[256];
    __shared__ int job_s;
    int tid = threadIdx.x;
    int l = tid & 63, w = tid >> 6;
    int lane15 = l & 15, g4 = l >> 4;
    const int xcd = blockIdx.x & 7;
    const int cmin = (C < 8) ? C : 8;
    const int ci = xcd % cmin;
    const int reps = (C >= 8) ? (C >> 3) : 1;
    int* ctr = jobc + ci;
    const int njobs = reps * S1T;

    short8 bfr1[2];
    float bb1[2];
#pragma unroll
    for (int ct = 0; ct < 2; ++ct) {
        int o16 = w * 32 + ct * 16 + lane15;
        bfr1[ct] = *reinterpret_cast<const short8*>(W1T2 + o16 * 32 + g4 * 8);
        bb1[ct] = b1l[o16];
    }

    for (;;) {
        if (tid == 0) job_s = atomicAdd(ctr, 1);
        __syncthreads();
        int job = job_s;
        if (job >= njobs) break;
        int rep = job / S1T;
        int tile = job - rep * S1T;
        int tl = ci + (rep << 3);
        const char* xq = x8_ + (size_t)tl * N_NODES * F_IN;
        char* h1q = (char*)h1q_ + (size_t)tl * S_Q8;
        int p = tile * 256 + tid;
        int node = (p < N_NODES) ? perm[p] : -1;
        pnode[tid] = node;

        float acc[16], rootv[16];
#pragma unroll
        for (int k = 0; k < 16; ++k) { acc[k] = 0.0f; rootv[k] = 0.0f; }
        if (node >= 0) {
            int d = degs2[p];
            const int base = tb[p >> 6] + (p & 63);
            int j = 0;
            for (; j + 2 <= d; j += 2) {
                int i0 = csr3[base + j * 64];
                int i1 = csr3[base + (j + 1) * 64];
                uint4 r0 = *reinterpret_cast<const uint4*>(xq + (size_t)i0 * F_IN);
                uint4 r1 = *reinterpret_cast<const uint4*>(xq + (size_t)i1 * F_IN);
#pragma unroll
                for (int c = 0; c < 4; ++c) {
                    uint v0 = c == 0 ? r0.x : c == 1 ? r0.y : c == 2 ? r0.z : r0.w;
                    uint v1 = c == 0 ? r1.x : c == 1 ? r1.y : c == 2 ? r1.z : r1.w;
                    f32x2 lo0 = __builtin_amdgcn_cvt_pk_f32_fp8((int)v0, false);
                    f32x2 hi0 = __builtin_amdgcn_cvt_pk_f32_fp8((int)v0, true);
                    f32x2 lo1 = __builtin_amdgcn_cvt_pk_f32_fp8((int)v1, false);
                    f32x2 hi1 = __builtin_amdgcn_cvt_pk_f32_fp8((int)v1, true);
                    acc[4 * c + 0] += lo0.x + lo1.x; acc[4 * c + 1] += lo0.y + lo1.y;
                    acc[4 * c + 2] += hi0.x + hi1.x; acc[4 * c + 3] += hi0.y + hi1.y;
                }
            }
            for (; j < d; ++j) {
                int idx = csr3[base + j * 64];
                uint4 row = *reinterpret_cast<const uint4*>(xq + (size_t)idx * F_IN);
#pragma unroll
                for (int c = 0; c < 4; ++c) {
                    uint vd = c == 0 ? row.x : c == 1 ? row.y : c == 2 ? row.z : row.w;
                    f32x2 lo = __builtin_amdgcn_cvt_pk_f32_fp8((int)vd, false);
                    f32x2 hi = __builtin_amdgcn_cvt_pk_f32_fp8((int)vd, true);
                    acc[4 * c + 0] += lo.x; acc[4 * c + 1] += lo.y;
                    acc[4 * c + 2] += hi.x; acc[4 * c + 3] += hi.y;
                }
            }
            float id = invd2[p] * INVQX;
#pragma unroll
            for (int k = 0; k < 16; ++k) acc[k] *= id;
            uint4 rv = *reinterpret_cast<const uint4*>(xq + (size_t)node * F_IN);
#pragma unroll
            for (int c = 0; c < 4; ++c) {
                uint vd = c == 0 ? rv.x : c == 1 ? rv.y : c == 2 ? rv.z : rv.w;
                f32x2 lo = __builtin_amdgcn_cvt_pk_f32_fp8((int)vd, false);
                f32x2 hi = __builtin_amdgcn_cvt_pk_f32_fp8((int)vd, true);
                rootv[4 * c + 0] = lo.x * INVQX; rootv[4 * c + 1] = lo.y * INVQX;
                rootv[4 * c + 2] = hi.x * INVQX; rootv[4 * c + 3] = hi.y * INVQX;
            }
        }
        {
            uint dw[16];
#pragma unroll
            for (int i = 0; i < 8; ++i)
                dw[i] = (uint)f2bf(acc[2 * i]) | ((uint)f2bf(acc[2 * i + 1]) << 16);
#pragma unroll
            for (int i = 0; i < 8; ++i)
                dw[8 + i] = (uint)f2bf(rootv[2 * i]) | ((uint)f2bf(rootv[2 * i + 1]) << 16);
            ushort* ur = u + tid * 40;
#pragma unroll
            for (int c = 0; c < 4; ++c)
                *reinterpret_cast<uint4*>(ur + c * 8) =
                    make_uint4(dw[4 * c], dw[4 * c + 1], dw[4 * c + 2], dw[4 * c + 3]);
        }
        __syncthreads();

#pragma unroll 4
        for (int rt = 0; rt < 16; ++rt) {
            int row = rt * 16 + lane15;
            short8 af = *reinterpret_cast<const short8*>(u + row * 40 + g4 * 8);
            f32x4 a0 = __builtin_amdgcn_mfma_f32_16x16x32_bf16(af, bfr1[0], (f32x4)(0.0f), 0, 0, 0);
            f32x4 a1 = __builtin_amdgcn_mfma_f32_16x16x32_bf16(af, bfr1[1], (f32x4)(0.0f), 0, 0, 0);
#pragma unroll
            for (int j = 0; j < 4; ++j) {
                int nl = rt * 16 + g4 * 4 + j;
                int nd = pnode[nl];
                if (nd >= 0) {
                    float v0 = fmaxf(a0[j] + bb1[0], 0.0f) * QSCALE;
                    float v1 = fmaxf(a1[j] + bb1[1], 0.0f) * QSCALE;
                    int q0 = __builtin_amdgcn_cvt_pk_fp8_f32(v0, v0, 0, false);
                    int q1 = __builtin_amdgcn_cvt_pk_fp8_f32(v1, v1, 0, false);
                    h1q[(size_t)nd * HGd + w * 32 + lane15] = (char)q0;
                    h1q[(size_t)nd * HGd + w * 32 + 16 + lane15] = (char)q1;
                }
            }
        }
    }
}

// ---------------- SAGE layer 2 (fp8 padded gather + bf16 MFMA, 64-node tiles) ----------------
__global__ __launch_bounds__(256) void k_sage2(
        const uchar1* __restrict__ h1q_,
        const int* __restrict__ rp2p, const int* __restrict__ csr2p,
        const float* __restrict__ invd2,
        const ushort* __restrict__ WT2, const float* __restrict__ b2l,
        const int* __restrict__ perm, float* __restrict__ HgP,
        int* __restrict__ jobc, int t0, int C) {
    __shared__ uint4 usm4[64 * 512 / 16];   // 32 KB
    __shared__ int pnode[64];
    __shared__ int job_s;
    char* ub = (char*)usm4;
    int tid = threadIdx.x;
    int l = tid & 63, w = tid >> 6;
    int lane15 = l & 15, g4 = l >> 4;
    const int xcd = blockIdx.x & 7;
    const int cmin = (C < 8) ? C : 8;
    const int ci = xcd % cmin;
    const int reps = (C >= 8) ? (C >> 3) : 1;
    int* ctr = jobc + ci;
    const int njobs = reps * NT64;

    short8 bfr[2][8];
    float bb[2];
#pragma unroll
    for (int ct = 0; ct < 2; ++ct) {
        int n = w * 32 + ct * 16 + lane15;
        const ushort* bp = WT2 + n * 256 + g4 * 8;
#pragma unroll
        for (int ks = 0; ks < 8; ++ks)
            bfr[ct][ks] = *reinterpret_cast<const short8*>(bp + ks * 32);
        bb[ct] = b2l[n];
    }

    for (;;) {
        if (tid == 0) job_s = atomicAdd(ctr, 1);
        __syncthreads();
        int job = job_s;
        if (job >= njobs) break;
        int rep = job / NT64;
        int tile = job - rep * NT64;
        int tl = ci + ((reps - 1 - rep) << 3);   // freshest slice first
        int t = t0 + tl;
        const char* h1q = (const char*)h1q_ + (size_t)tl * S_Q8;
        int nbase = tile * 64;
        if (tid < 64) {
            int p = nbase + tid;
            pnode[tid] = (p < N_NODES) ? perm[p] : N_NODES;   // zero row if invalid
        }
        __syncthreads();

        // root rows (fp8 -> bf16*INVQ): 64 rows x 8 segs of 16 fp8
        {
            int nl = tid >> 2, sg2 = tid & 3;     // 64 rows x 4 pairs of segs
#pragma unroll
            for (int h = 0; h < 2; ++h) {
                int seg = sg2 * 2 + h;
                uint4 v = *reinterpret_cast<const uint4*>(h1q + (size_t)pnode[nl] * HGd + seg * 16);
                uint bw[8];
#pragma unroll
                for (int d = 0; d < 4; ++d) {
                    uint vd = d == 0 ? v.x : d == 1 ? v.y : d == 2 ? v.z : v.w;
                    f32x2 plo = __builtin_amdgcn_cvt_pk_f32_fp8((int)vd, false);
                    f32x2 phi = __builtin_amdgcn_cvt_pk_f32_fp8((int)vd, true);
                    bw[2 * d]     = (uint)f2bf(plo.x * INVQ) | ((uint)f2bf(plo.y * INVQ) << 16);
                    bw[2 * d + 1] = (uint)f2bf(phi.x * INVQ) | ((uint)f2bf(phi.y * INVQ) << 16);
                }
                int base = nl * 512 + 256 + seg * 32;
                int swz = (nl & 7) << 4;
                *reinterpret_cast<uint4*>(ub + (base ^ swz)) =
                    make_uint4(bw[0], bw[1], bw[2], bw[3]);
                *reinterpret_cast<uint4*>(ub + ((base + 16) ^ swz)) =
                    make_uint4(bw[4], bw[5], bw[6], bw[7]);
            }
        }

        // gather (fp8, padded, no clamps): wave w -> 16 nodes, 4 passes of 4; unroll-8
#pragma unroll
        for (int g = 0; g < 4; ++g) {
            int nl = w * 16 + g * 4 + g4;
            int p2 = nbase + nl;
            int sl = 0, dp = 0;
            if (p2 < N_NODES) { sl = rp2p[p2]; dp = rp2p[p2 + 1] - sl; }
            const int* cp = csr2p + sl;
            float af[8] = {0, 0, 0, 0, 0, 0, 0, 0};
            if (dp > 0) {
                int idx[8];
#pragma unroll
                for (int uu = 0; uu < 8; ++uu) idx[uu] = cp[uu];
                for (int j = 0; j < dp; j += 8) {
                    uint2 vv[8];
#pragma unroll
                    for (int uu = 0; uu < 8; ++uu)
                        vv[uu] = *reinterpret_cast<const uint2*>(h1q + (size_t)idx[uu] * HGd + lane15 * 8);
                    cp += 8;
#pragma unroll
                    for (int uu = 0; uu < 8; ++uu) idx[uu] = cp[uu];   // guard ints past end
#pragma unroll
                    for (int uu = 0; uu < 8; ++uu) {
                        f32x2 p0 = __builtin_amdgcn_cvt_pk_f32_fp8((int)vv[uu].x, false);
                        f32x2 p1 = __builtin_amdgcn_cvt_pk_f32_fp8((int)vv[uu].x, true);
                        f32x2 p2v = __builtin_amdgcn_cvt_pk_f32_fp8((int)vv[uu].y, false);
                        f32x2 p3 = __builtin_amdgcn_cvt_pk_f32_fp8((int)vv[uu].y, true);
                        af[0] += p0.x; af[1] += p0.y; af[2] += p1.x; af[3] += p1.y;
                        af[4] += p2v.x; af[5] += p2v.y; af[6] += p3.x; af[7] += p3.y;
                    }
                }
            }
            float id = (p2 < N_NODES) ? invd2[p2] * INVQ : 0.0f;
            uint4 pk;
            pk.x = (uint)f2bf(af[0] * id) | ((uint)f2bf(af[1] * id) << 16);
            pk.y = (uint)f2bf(af[2] * id) | ((uint)f2bf(af[3] * id) << 16);
            pk.z = (uint)f2bf(af[4] * id) | ((uint)f2bf(af[5] * id) << 16);
            pk.w = (uint)f2bf(af[6] * id) | ((uint)f2bf(af[7] * id) << 16);
            *reinterpret_cast<uint4*>(ub + ((nl * 512 + lane15 * 16) ^ ((nl & 7) << 4))) = pk;
        }
        __syncthreads();

        f32x4 acc[4][2];
#pragma unroll
        for (int rt = 0; rt < 4; ++rt)
#pragma unroll
            for (int ct = 0; ct < 2; ++ct) acc[rt][ct] = (f32x4)(0.0f);
#pragma unroll
        for (int ks = 0; ks < 8; ++ks) {
#pragma unroll
            for (int rt = 0; rt < 4; ++rt) {
                int row = rt * 16 + lane15;
                int byt = (row * 512 + (ks * 32 + g4 * 8) * 2) ^ ((row & 7) << 4);
                short8 af = *reinterpret_cast<const short8*>(ub + byt);
                acc[rt][0] = __builtin_amdgcn_mfma_f32_16x16x32_bf16(af, bfr[0][ks], acc[rt][0], 0, 0, 0);
                acc[rt][1] = __builtin_amdgcn_mfma_f32_16x16x32_bf16(af, bfr[1][ks], acc[rt][1], 0, 0, 0);
            }
        }
#pragma unroll
        for (int ct = 0; ct < 2; ++ct) {
            float sum = 0.f;
#pragma unroll
            for (int rt = 0; rt < 4; ++rt)
#pragma unroll
                for (int j = 0; j < 4; ++j) {
                    int rowi = rt * 16 + g4 * 4 + j;
                    float v = fmaxf(acc[rt][ct][j] + bb[ct], 0.f);
                    sum += (nbase + rowi < N_NODES) ? v : 0.f;
                }
            sum += __shfl_xor(sum, 16);
            sum += __shfl_xor(sum, 32);
            if (g4 == 0) {
                int n = w * 32 + ct * 16 + lane15;
                atomicAdd(&HgP[(t * 8 + (tile & 7)) * HGd + n], sum);
            }
        }
    }
}

// ---------------- GRU input gates ----------------
__global__ __launch_bounds__(768) void k_gi(const float* __restrict__ HgP,
        const float* __restrict__ WihT, const float* __restrict__ b_ih,
        float* __restrict__ gi_all) {
    __shared__ float x[HGd];
    int t = blockIdx.x, g = threadIdx.x;
    if (g < HGd) {
        float s = 0.f;
#pragma unroll
        for (int p = 0; p < 8; ++p) s += HgP[(t * 8 + p) * HGd + g];
        x[g] = s * INVN;
    }
    __syncthreads();
    float a = b_ih[g];
    for (int k = 0; k < HGd; ++k) a += WihT[k * 768 + g] * x[k];
    gi_all[t * 768 + g] = a;
}

// ---------------- single-block GRU + head ----------------
__global__ __launch_bounds__(768, 3) void k_gru1b(const float* __restrict__ gi_all,
        const uint* __restrict__ W_hhq, const float* __restrict__ b_hh,
        const float* __restrict__ Wh1, const float* __restrict__ bh1,
        const float* __restrict__ Wh2, const float* __restrict__ bh2,
        float* __restrict__ out) {
    int tid = threadIdx.x;
    uint wv[128];
#pragma unroll
    for (int i = 0; i < 128; ++i) wv[i] = W_hhq[i * 768 + tid];
    float bh = b_hh[tid];

    __shared__ float hs[HTd];
    __shared__ uint h2s[HTd / 2];
    __shared__ float gh[3 * HTd];
    if (tid < HTd) hs[tid] = 0.0f;
    if (tid < HTd / 2) h2s[tid] = 0u;
    __syncthreads();

    for (int t = 0; t < T_STEPS; ++t) {
        float s = bh;
#pragma unroll
        for (int i = 0; i < 128; i += 4) {
            uint4 hh = *reinterpret_cast<const uint4*>(&h2s[i]);
            s = __builtin_amdgcn_fdot2(u2h(wv[i + 0]), u2h(hh.x), s, false);
            s = __builtin_amdgcn_fdot2(u2h(wv[i + 1]), u2h(hh.y), s, false);
            s = __builtin_amdgcn_fdot2(u2h(wv[i + 2]), u2h(hh.z), s, false);
            s = __builtin_amdgcn_fdot2(u2h(wv[i + 3]), u2h(hh.w), s, false);
        }
        gh[tid] = s;
        __syncthreads();
        if (tid < HTd) {
            float gir = gi_all[t * 768 + tid];
            float giz = gi_all[t * 768 + HTd + tid];
            float gin = gi_all[t * 768 + 2 * HTd + tid];
            float r = 1.0f / (1.0f + expf(-(gir + gh[tid])));
            float z = 1.0f / (1.0f + expf(-(giz + gh[HTd + tid])));
            float n = tanhf(gin + r * gh[2 * HTd + tid]);
            hs[tid] = (1.0f - z) * n + z * hs[tid];
        }
        __syncthreads();
        if (tid < HTd / 2)
            h2s[tid] = packf16(hs[2 * tid], hs[2 * tid + 1]);
        __syncthreads();
    }

    __shared__ float act[64];
    if (tid < 64) {
        float a = bh1[tid];
        const float* wr = Wh1 + tid * HTd;
        for (int k = 0; k < HTd; k += 4) {
            float4 wv4 = *reinterpret_cast<const float4*>(wr + k);
            a += wv4.x * hs[k] + wv4.y * hs[k + 1] + wv4.z * hs[k + 2] + wv4.w * hs[k + 3];
        }
        act[tid] = fmaxf(a, 0.0f);
    }
    __syncthreads();
    if (tid == 0) {
        float y = bh2[0];
        for (int j = 0; j < 64; ++j) y += Wh2[j] * act[j];
        out[0] = y;
    }
}

// ---------------- launch ----------------
extern "C" void kernel_launch(void* const* d_in, const int* in_sizes, int n_in,
                              void* d_out, int out_size, void* d_ws, size_t ws_size,
                              hipStream_t stream) {
    const float* x_seq = (const float*)d_in[0];
    const int*   ei    = (const int*)d_in[1];
    const float* W1l   = (const float*)d_in[2];
    const float* b1l   = (const float*)d_in[3];
    const float* W1r   = (const float*)d_in[4];
    const float* W2l   = (const float*)d_in[5];
    const float* b2l   = (const float*)d_in[6];
    const float* W2r   = (const float*)d_in[7];
    const float* W_ih  = (const float*)d_in[8];
    const float* W_hh  = (const float*)d_in[9];
    const float* b_ih  = (const float*)d_in[10];
    const float* b_hh  = (const float*)d_in[11];
    const float* Wh1   = (const float*)d_in[12];
    const float* bh1   = (const float*)d_in[13];
    const float* Wh2   = (const float*)d_in[14];
    const float* bh2   = (const float*)d_in[15];
    float* out = (float*)d_out;

    char* ws = (char*)d_ws;
    size_t off = 0;
    auto take = [&](size_t nbytes) -> void* {
        void* p = (void*)(ws + off);
        off += (nbytes + 255) & ~(size_t)255;
        return p;
    };
    int*    deg    = (int*)take(N_NODES * 4);
    int*    rp     = (int*)take((N_NODES + 1) * 4);
    int*    cursor = (int*)take(N_NODES * 4);
    int*    csr    = (int*)take(N_EDGES * 4);
    float*  invd   = (float*)take(N_NODES * 4);
    int*    perm   = (int*)take(N_NODES * 4);
    int*    pos    = (int*)take(N_NODES * 4);
    int*    rp2    = (int*)take((N_NODES + 2) * 4);
    int*    rp2p   = (int*)take((N_NODES + 2) * 4);
    int*    csr2p  = (int*)take(480300 * 4);
    float*  invd2  = (float*)take(N_NODES * 4);
    int*    degs2  = (int*)take(N_NODES * 4);
    int*    tb     = (int*)take(520 * 4);
    int*    csr3   = (int*)take(360000 * 4);
    int*    bins   = (int*)take(256 * 4);
    int*    bincur = (int*)take(256 * 4);
    int*    nodeb  = (int*)take(256 * 4);
    int*    edgeb  = (int*)take(256 * 4);
    int*    edgebp = (int*)take(256 * 4);
    ushort* W1T2   = (ushort*)take(128 * 32 * 2);
    ushort* WT2    = (ushort*)take(128 * 256 * 2);
    float*  WihT   = (float*)take(128 * 768 * 4);
    uint*   W_hhq  = (uint*)take(128 * 768 * 4);
    float*  HgP    = (float*)take(T_STEPS * 8 * HGd * 4);
    float*  gi_all = (float*)take(T_STEPS * 768 * 4);
    int*    jobc   = (int*)take(1024 * 4);

    const size_t slice_q = (S_Q8 + 255) & ~(size_t)255;                      // 2.56 MB
    const size_t slice_x = ((size_t)N_NODES * F_IN + 255) & ~(size_t)255;    // 320 KB
    int T_CH = 64;
    while (T_CH > 1 && off + (size_t)T_CH * (slice_q + slice_x) > ws_size)
        T_CH >>= 1;
    uchar1* h1q = (uchar1*)take((size_t)T_CH * slice_q);
    char*   x8  = (char*)take((size_t)T_CH * slice_x);

    k_zero<<<256, 256, 0, stream>>>(deg, HgP, jobc, bins, (uint*)h1q, T_CH);
    k_degree<<<(N_EDGES + 255) / 256, 256, 0, stream>>>(ei, deg);
    k_scan<<<1, 1024, 0, stream>>>(deg, rp, cursor, invd);
    k_fill<<<(N_EDGES + 255) / 256, 256, 0, stream>>>(ei, cursor, csr);
    k_hist<<<(N_NODES + 255) / 256, 256, 0, stream>>>(deg, bins);
    k_binscan<<<1, 256, 0, stream>>>(bins, bincur, nodeb, edgeb, edgebp, rp2p);
    k_perm<<<(N_NODES + 255) / 256, 256, 0, stream>>>(deg, bincur, nodeb, edgeb, edgebp,
                                                      invd, perm, pos, rp2, invd2, degs2, rp2p);
    k_tb<<<1, 512, 0, stream>>>(rp2, tb);
    k_ecopy<<<(N_EDGES + 255) / 256, 256, 0, stream>>>(rp, pos, rp2p, tb, csr, csr3, csr2p);
    k_pad<<<(N_NODES + 255) / 256, 256, 0, stream>>>(rp, pos, rp2p, csr2p);
    {
        int total = 128 * 32 + 128 * 256 + 128 * 768 + 128 * 768;
        k_prepw<<<(total + 255) / 256, 256, 0, stream>>>(W1l, W1r, W2l, W2r, W_ih, W_hh,
                                                         W1T2, WT2, WihT, W_hhq);
    }
    int chunk = 0;
    for (int t0 = 0; t0 < T_STEPS; t0 += T_CH, ++chunk) {
        int C = T_CH;
        int n4 = C * N_NODES * F_IN / 4;
        k_qx<<<(n4 + 255) / 256, 256, 0, stream>>>(
            x_seq + (size_t)t0 * N_NODES * F_IN, (int*)x8, n4);
        k_sage1<<<2048, 256, 0, stream>>>(x8, tb, csr3, degs2, invd2, W1T2, b1l, perm,
                                          h1q, jobc + chunk * 32, C);
        k_sage2<<<2048, 256, 0, stream>>>(h1q, rp2p, csr2p, invd2, WT2, b2l, perm, HgP,
                                          jobc + chunk * 32 + 16, t0, C);
    }
    k_gi<<<T_STEPS, 768, 0, stream>>>(HgP, WihT, b_ih, gi_all);
    k_gru1b<<<1, 768, 0, stream>>>(gi_all, W_hhq, b_hh, Wh1, bh1, Wh2, bh2, out);
}

// Round 19
// 1086.669 us; speedup vs baseline: 1.1942x; 1.1942x over previous
//
#include <hip/hip_runtime.h>
#include <hip/hip_bf16.h>

#define N_NODES 20000
#define N_EDGES 320000
#define T_STEPS 64
#define F_IN    16
#define HGd     128
#define HTd     256
#define INVN    (1.0f/20000.0f)
#define NTILES   625
#define S1T      79
#define NG64     313
#define QSCALE   64.0f
#define INVQ     (1.0f/64.0f)
#define QX       32.0f
#define INVQX    (1.0f/32.0f)
#define S_Q8     ((size_t)(N_NODES + 1) * HGd)   // fp8 slice stride incl. zero row

typedef __attribute__((ext_vector_type(8))) short short8;
typedef __attribute__((ext_vector_type(4))) float f32x4;
typedef __attribute__((ext_vector_type(2))) float f32x2;
typedef __attribute__((ext_vector_type(2))) _Float16 half2t;

static __device__ __forceinline__ ushort f2bf(float f) {
    __hip_bfloat16 b = __float2bfloat16(f);
    return *reinterpret_cast<ushort*>(&b);
}
static __device__ __forceinline__ half2t u2h(uint u) {
    half2t h; __builtin_memcpy(&h, &u, 4); return h;
}
static __device__ __forceinline__ uint packf16(float a, float b) {
    auto h = __builtin_amdgcn_cvt_pkrtz(a, b);
    uint u; __builtin_memcpy(&u, &h, 4); return u;
}

// ---------------- init ----------------
__global__ void k_zero(int* __restrict__ deg, float* __restrict__ HgP,
                       int* __restrict__ jobc, int* __restrict__ bins,
                       uint* __restrict__ h1q, int tch) {
    int i = blockIdx.x * blockDim.x + threadIdx.x;
    if (i < N_NODES) deg[i] = 0;
    if (i < T_STEPS * 8 * HGd) HgP[i] = 0.0f;
    if (i < 1024) jobc[i] = 0;
    if (i < 256) bins[i] = 0;
    if (i < tch * 32) {          // zero row N_NODES of each fp8 slice (32 uints)
        int sl = i >> 5, j = i & 31;
        h1q[sl * (S_Q8 / 4) + (size_t)N_NODES * (HGd / 4) + j] = 0u;
    }
}

__global__ void k_degree(const int* __restrict__ ei, int* __restrict__ deg) {
    int e = blockIdx.x * blockDim.x + threadIdx.x;
    if (e < N_EDGES) atomicAdd(&deg[ei[N_EDGES + e]], 1);
}

__global__ __launch_bounds__(1024) void k_scan(const int* __restrict__ deg,
        int* __restrict__ rp, int* __restrict__ cursor, float* __restrict__ invd) {
    __shared__ int sh[1024];
    __shared__ int carry_s;
    int tid = threadIdx.x;
    if (tid == 0) { carry_s = 0; rp[0] = 0; }
    __syncthreads();
    for (int base = 0; base < N_NODES; base += 1024) {
        int i = base + tid;
        int v = (i < N_NODES) ? deg[i] : 0;
        sh[tid] = v;
        __syncthreads();
        for (int off = 1; off < 1024; off <<= 1) {
            int t = (tid >= off) ? sh[tid - off] : 0;
            __syncthreads();
            sh[tid] += t;
            __syncthreads();
        }
        int inc = sh[tid] + carry_s;
        if (i < N_NODES) {
            rp[i + 1] = inc;
            cursor[i] = inc - v;
            invd[i] = (v > 0) ? (1.0f / (float)v) : 0.0f;
        }
        __syncthreads();
        if (tid == 1023) carry_s = inc;
        __syncthreads();
    }
}

__global__ void k_fill(const int* __restrict__ ei, int* __restrict__ cursor,
                       int* __restrict__ csr) {
    int e = blockIdx.x * blockDim.x + threadIdx.x;
    if (e < N_EDGES) {
        int d = ei[N_EDGES + e];
        int p = atomicAdd(&cursor[d], 1);
        csr[p] = ei[e];
    }
}

// ---------------- degree-sort permutation ----------------
__global__ void k_hist(const int* __restrict__ deg, int* __restrict__ bins) {
    int i = blockIdx.x * blockDim.x + threadIdx.x;
    if (i < N_NODES) atomicAdd(&bins[min(deg[i], 255)], 1);
}

__global__ __launch_bounds__(256) void k_binscan(const int* __restrict__ bins,
        int* __restrict__ bincur, int* __restrict__ nodebefore,
        int* __restrict__ edgebefore, int* __restrict__ edgebp, int* __restrict__ rp2p) {
    __shared__ int sh[256], she[256], shp[256];
    int tid = threadIdx.x;
    int b = bins[tid];
    int dp = (tid + 7) & ~7;
    sh[tid] = b;
    she[tid] = b * tid;
    shp[tid] = b * dp;
    __syncthreads();
    for (int off = 1; off < 256; off <<= 1) {
        int v = (tid >= off) ? sh[tid - off] : 0;
        int ve = (tid >= off) ? she[tid - off] : 0;
        int vp = (tid >= off) ? shp[tid - off] : 0;
        __syncthreads();
        sh[tid] += v; she[tid] += ve; shp[tid] += vp;
        __syncthreads();
    }
    bincur[tid] = sh[tid] - b;
    nodebefore[tid] = sh[tid] - b;
    edgebefore[tid] = she[tid] - b * tid;
    edgebp[tid] = shp[tid] - b * dp;
    if (tid == 255) rp2p[N_NODES] = shp[255];
}

__global__ void k_perm(const int* __restrict__ deg, int* __restrict__ bincur,
                       const int* __restrict__ nodebefore, const int* __restrict__ edgebefore,
                       const int* __restrict__ edgebp, const float* __restrict__ invd,
                       int* __restrict__ perm, int* __restrict__ pos,
                       int* __restrict__ rp2, float* __restrict__ invd2,
                       int* __restrict__ degs2, int* __restrict__ rp2p) {
    int i = blockIdx.x * blockDim.x + threadIdx.x;
    if (i < N_NODES) {
        int d = min(deg[i], 255);
        int p = atomicAdd(&bincur[d], 1);
        int rank = p - nodebefore[d];
        perm[p] = i;
        pos[i] = p;
        rp2[p] = edgebefore[d] + rank * d;
        rp2p[p] = edgebp[d] + rank * ((d + 7) & ~7);
        invd2[p] = invd[i];
        degs2[p] = deg[i];
        if (i == 0) rp2[N_NODES] = N_EDGES;
    }
}

// per-64-group transposed edge-list bases (sage1)
__global__ __launch_bounds__(512) void k_tb(const int* __restrict__ rp2, int* __restrict__ tb) {
    __shared__ int sh[512];
    int t = threadIdx.x;
    int md = 0;
    if (t < NG64 && t * 64 < N_NODES) {
        int last = min((t + 1) * 64, N_NODES) - 1;
        md = rp2[last + 1] - rp2[last];
    }
    sh[t] = 64 * md;
    __syncthreads();
    for (int off = 1; off < 512; off <<= 1) {
        int v = (t >= off) ? sh[t - off] : 0;
        __syncthreads();
        sh[t] += v;
        __syncthreads();
    }
    tb[t + 1] = sh[t];
    if (t == 0) tb[0] = 0;
}

// edge-parallel scatter into csr3 (sage1) and csr2p (sage2 padded)
__global__ void k_ecopy(const int* __restrict__ rp, const int* __restrict__ pos,
                        const int* __restrict__ rp2p, const int* __restrict__ tb,
                        const int* __restrict__ csr,
                        int* __restrict__ csr3, int* __restrict__ csr2p) {
    int e = blockIdx.x * blockDim.x + threadIdx.x;
    if (e < N_EDGES) {
        int lo = 0, hi = N_NODES - 1;
#pragma unroll
        for (int it = 0; it < 15; ++it) {
            int mid = (lo + hi + 1) >> 1;
            if (rp[mid] <= e) lo = mid; else hi = mid - 1;
        }
        int i = lo;
        int j = e - rp[i];
        int p = pos[i];
        int v = csr[e];
        csr3[tb[p >> 6] + j * 64 + (p & 63)] = v;
        csr2p[rp2p[p] + j] = v;
    }
}

__global__ void k_pad(const int* __restrict__ rp, const int* __restrict__ pos,
                      const int* __restrict__ rp2p, int* __restrict__ csr2p) {
    int i = blockIdx.x * blockDim.x + threadIdx.x;
    if (i < N_NODES) {
        int d = rp[i + 1] - rp[i];
        int dp = (d + 7) & ~7;
        int o = rp2p[pos[i]];
        for (int k = d; k < dp; ++k) csr2p[o + k] = N_NODES;   // fp8 zero row
    }
}

// ---------------- x_seq fp32 -> fp8 (x32) ----------------
__global__ void k_qx(const float* __restrict__ xs, int* __restrict__ x8, int n4) {
    int i = blockIdx.x * blockDim.x + threadIdx.x;
    if (i < n4) {
        float4 v = reinterpret_cast<const float4*>(xs)[i];
        int q8 = __builtin_amdgcn_cvt_pk_fp8_f32(v.x * QX, v.y * QX, 0, false);
        q8 = __builtin_amdgcn_cvt_pk_fp8_f32(v.z * QX, v.w * QX, q8, true);
        x8[i] = q8;
    }
}

// ---------------- weight prep ----------------
__global__ void k_prepw(const float* __restrict__ W1l, const float* __restrict__ W1r,
                        const float* __restrict__ W2l, const float* __restrict__ W2r,
                        const float* __restrict__ W_ih, const float* __restrict__ W_hh,
                        ushort* __restrict__ W1T2, ushort* __restrict__ WT2,
                        float* __restrict__ WihT, uint* __restrict__ W_hhq) {
    int i = blockIdx.x * blockDim.x + threadIdx.x;
    const int n1 = 128 * 32, n2 = 128 * 256, n3 = 128 * 768, n4 = 128 * 768;
    if (i < n1) {
        int o = i >> 5, k = i & 31;
        float v = (k < 16) ? W1l[o * 16 + k] : W1r[o * 16 + (k - 16)];
        W1T2[i] = f2bf(v);
    } else if (i < n1 + n2) {
        int j = i - n1; int o = j >> 8, k = j & 255;
        float v = (k < 128) ? W2l[o * 128 + k] : W2r[o * 128 + (k - 128)];
        WT2[j] = f2bf(v);
    } else if (i < n1 + n2 + n3) {
        int j = i - n1 - n2; int k = j / 768, g = j % 768;
        WihT[j] = W_ih[g * 128 + k];
    } else if (i < n1 + n2 + n3 + n4) {
        int j = i - n1 - n2 - n3; int dw = j / 768, row = j % 768;
        float a = W_hh[(size_t)row * HTd + 2 * dw];
        float b = W_hh[(size_t)row * HTd + 2 * dw + 1];
        W_hhq[j] = packf16(a, b);
    }
}

// ---------------- SAGE layer 1 (lane-per-node fp8 gather + bf16 MFMA -> fp8 h1) ----------------
__global__ __launch_bounds__(256) void k_sage1(
        const char* __restrict__ x8_, const int* __restrict__ tb,
        const int* __restrict__ csr3, const int* __restrict__ degs2,
        const float* __restrict__ invd2,
        const ushort* __restrict__ W1T2, const float* __restrict__ b1l,
        const int* __restrict__ perm, uchar1* __restrict__ h1q_,
        int* __restrict__ jobc, int C) {
    __shared__ ushort u[256 * 40];
    __shared__ int pnode[256];
    __shared__ int job_s;
    int tid = threadIdx.x;
    int l = tid & 63, w = tid >> 6;
    int lane15 = l & 15, g4 = l >> 4;
    const int xcd = blockIdx.x & 7;
    const int cmin = (C < 8) ? C : 8;
    const int ci = xcd % cmin;
    const int reps = (C >= 8) ? (C >> 3) : 1;
    int* ctr = jobc + ci;
    const int njobs = reps * S1T;

    short8 bfr1[2];
    float bb1[2];
#pragma unroll
    for (int ct = 0; ct < 2; ++ct) {
        int o16 = w * 32 + ct * 16 + lane15;
        bfr1[ct] = *reinterpret_cast<const short8*>(W1T2 + o16 * 32 + g4 * 8);
        bb1[ct] = b1l[o16];
    }

    for (;;) {
        if (tid == 0) job_s = atomicAdd(ctr, 1);
        __syncthreads();
        int job = job_s;
        if (job >= njobs) break;
        int rep = job / S1T;
        int tile = job - rep * S1T;
        int tl = ci + (rep << 3);
        const char* xq = x8_ + (size_t)tl * N_NODES * F_IN;
        char* h1q = (char*)h1q_ + (size_t)tl * S_Q8;
        int p = tile * 256 + tid;
        int node = (p < N_NODES) ? perm[p] : -1;
        pnode[tid] = node;

        float acc[16], rootv[16];
#pragma unroll
        for (int k = 0; k < 16; ++k) { acc[k] = 0.0f; rootv[k] = 0.0f; }
        if (node >= 0) {
            int d = degs2[p];
            const int base = tb[p >> 6] + (p & 63);
            for (int j = 0; j < d; ++j) {
                int idx = csr3[base + j * 64];
                uint4 row = *reinterpret_cast<const uint4*>(xq + (size_t)idx * F_IN);
#pragma unroll
                for (int c = 0; c < 4; ++c) {
                    uint vd = c == 0 ? row.x : c == 1 ? row.y : c == 2 ? row.z : row.w;
                    f32x2 lo = __builtin_amdgcn_cvt_pk_f32_fp8((int)vd, false);
                    f32x2 hi = __builtin_amdgcn_cvt_pk_f32_fp8((int)vd, true);
                    acc[4 * c + 0] += lo.x; acc[4 * c + 1] += lo.y;
                    acc[4 * c + 2] += hi.x; acc[4 * c + 3] += hi.y;
                }
            }
            float id = invd2[p] * INVQX;
#pragma unroll
            for (int k = 0; k < 16; ++k) acc[k] *= id;
            uint4 rv = *reinterpret_cast<const uint4*>(xq + (size_t)node * F_IN);
#pragma unroll
            for (int c = 0; c < 4; ++c) {
                uint vd = c == 0 ? rv.x : c == 1 ? rv.y : c == 2 ? rv.z : rv.w;
                f32x2 lo = __builtin_amdgcn_cvt_pk_f32_fp8((int)vd, false);
                f32x2 hi = __builtin_amdgcn_cvt_pk_f32_fp8((int)vd, true);
                rootv[4 * c + 0] = lo.x * INVQX; rootv[4 * c + 1] = lo.y * INVQX;
                rootv[4 * c + 2] = hi.x * INVQX; rootv[4 * c + 3] = hi.y * INVQX;
            }
        }
        {
            uint dw[16];
#pragma unroll
            for (int i = 0; i < 8; ++i)
                dw[i] = (uint)f2bf(acc[2 * i]) | ((uint)f2bf(acc[2 * i + 1]) << 16);
#pragma unroll
            for (int i = 0; i < 8; ++i)
                dw[8 + i] = (uint)f2bf(rootv[2 * i]) | ((uint)f2bf(rootv[2 * i + 1]) << 16);
            ushort* ur = u + tid * 40;
#pragma unroll
            for (int c = 0; c < 4; ++c)
                *reinterpret_cast<uint4*>(ur + c * 8) =
                    make_uint4(dw[4 * c], dw[4 * c + 1], dw[4 * c + 2], dw[4 * c + 3]);
        }
        __syncthreads();

#pragma unroll 4
        for (int rt = 0; rt < 16; ++rt) {
            int row = rt * 16 + lane15;
            short8 af = *reinterpret_cast<const short8*>(u + row * 40 + g4 * 8);
            f32x4 a0 = __builtin_amdgcn_mfma_f32_16x16x32_bf16(af, bfr1[0], (f32x4)(0.0f), 0, 0, 0);
            f32x4 a1 = __builtin_amdgcn_mfma_f32_16x16x32_bf16(af, bfr1[1], (f32x4)(0.0f), 0, 0, 0);
#pragma unroll
            for (int j = 0; j < 4; ++j) {
                int nl = rt * 16 + g4 * 4 + j;
                int nd = pnode[nl];
                if (nd >= 0) {
                    float v0 = fmaxf(a0[j] + bb1[0], 0.0f) * QSCALE;
                    float v1 = fmaxf(a1[j] + bb1[1], 0.0f) * QSCALE;
                    int q0 = __builtin_amdgcn_cvt_pk_fp8_f32(v0, v0, 0, false);
                    int q1 = __builtin_amdgcn_cvt_pk_fp8_f32(v1, v1, 0, false);
                    h1q[(size_t)nd * HGd + w * 32 + lane15] = (char)q0;
                    h1q[(size_t)nd * HGd + w * 32 + 16 + lane15] = (char)q1;
                }
            }
        }
    }
}

// ---------------- SAGE layer 2 (fp8 padded gather + bf16 MFMA, streamed B) ----------------
__global__ __launch_bounds__(256) void k_sage2(
        const uchar1* __restrict__ h1q_,
        const int* __restrict__ rp2p, const int* __restrict__ csr2p,
        const float* __restrict__ invd2,
        const ushort* __restrict__ WT2, const float* __restrict__ b2l,
        const int* __restrict__ perm, float* __restrict__ HgP,
        int* __restrict__ jobc, int t0, int C) {
    __shared__ uint4 usm4[32 * 512 / 16];
    __shared__ int pnode[32];
    __shared__ int job_s;
    char* ub = (char*)usm4;
    int tid = threadIdx.x;
    int l = tid & 63, w = tid >> 6;
    int lane15 = l & 15, g4 = l >> 4;
    const int xcd = blockIdx.x & 7;
    const int cmin = (C < 8) ? C : 8;
    const int ci = xcd % cmin;
    const int reps = (C >= 8) ? (C >> 3) : 1;
    int* ctr = jobc + ci;
    const int njobs = reps * NTILES;

    // streamed B-fragments: per-lane base pointers only (saves 64 VGPRs vs cache)
    const ushort* bp0 = WT2 + (w * 32 + lane15) * 256 + g4 * 8;
    const ushort* bp1 = WT2 + (w * 32 + 16 + lane15) * 256 + g4 * 8;
    float bb0 = b2l[w * 32 + lane15];
    float bb1v = b2l[w * 32 + 16 + lane15];

    for (;;) {
        if (tid == 0) job_s = atomicAdd(ctr, 1);
        __syncthreads();
        int job = job_s;
        if (job >= njobs) break;
        int rep = job / NTILES;
        int tile = job - rep * NTILES;
        int tl = ci + ((reps - 1 - rep) << 3);   // freshest slice first
        int t = t0 + tl;
        const char* h1q = (const char*)h1q_ + (size_t)tl * S_Q8;
        int nbase = tile * 32;
        if (tid < 32) pnode[tid] = perm[nbase + tid];
        __syncthreads();

        // root rows (fp8 -> bf16*INVQ)
        {
            int nl = tid >> 3, seg = tid & 7;
            uint4 v = *reinterpret_cast<const uint4*>(h1q + (size_t)pnode[nl] * HGd + seg * 16);
            uint bw[8];
#pragma unroll
            for (int d = 0; d < 4; ++d) {
                uint vd = d == 0 ? v.x : d == 1 ? v.y : d == 2 ? v.z : v.w;
                f32x2 plo = __builtin_amdgcn_cvt_pk_f32_fp8((int)vd, false);
                f32x2 phi = __builtin_amdgcn_cvt_pk_f32_fp8((int)vd, true);
                bw[2 * d]     = (uint)f2bf(plo.x * INVQ) | ((uint)f2bf(plo.y * INVQ) << 16);
                bw[2 * d + 1] = (uint)f2bf(phi.x * INVQ) | ((uint)f2bf(phi.y * INVQ) << 16);
            }
            int base = nl * 512 + 256 + seg * 32;
            int swz = (nl & 7) << 4;
            *reinterpret_cast<uint4*>(ub + (base ^ swz)) =
                make_uint4(bw[0], bw[1], bw[2], bw[3]);
            *reinterpret_cast<uint4*>(ub + ((base + 16) ^ swz)) =
                make_uint4(bw[4], bw[5], bw[6], bw[7]);
        }

        // gather (fp8, padded, no clamps): wave w -> 8 nodes, 2 passes of 4; unroll-4
#pragma unroll
        for (int g = 0; g < 2; ++g) {
            int nl = w * 8 + g * 4 + g4;
            int sl = rp2p[nbase + nl];
            int dp = rp2p[nbase + nl + 1] - sl;
            const int* cp = csr2p + sl;
            float af[8] = {0, 0, 0, 0, 0, 0, 0, 0};
            if (dp > 0) {
                int idx[4];
#pragma unroll
                for (int uu = 0; uu < 4; ++uu) idx[uu] = cp[uu];
                for (int j = 0; j < dp; j += 4) {
                    uint2 vv[4];
#pragma unroll
                    for (int uu = 0; uu < 4; ++uu)
                        vv[uu] = *reinterpret_cast<const uint2*>(h1q + (size_t)idx[uu] * HGd + lane15 * 8);
                    cp += 4;
#pragma unroll
                    for (int uu = 0; uu < 4; ++uu) idx[uu] = cp[uu];   // guard ints past end
#pragma unroll
                    for (int uu = 0; uu < 4; ++uu) {
                        f32x2 p0 = __builtin_amdgcn_cvt_pk_f32_fp8((int)vv[uu].x, false);
                        f32x2 p1 = __builtin_amdgcn_cvt_pk_f32_fp8((int)vv[uu].x, true);
                        f32x2 p2 = __builtin_amdgcn_cvt_pk_f32_fp8((int)vv[uu].y, false);
                        f32x2 p3 = __builtin_amdgcn_cvt_pk_f32_fp8((int)vv[uu].y, true);
                        af[0] += p0.x; af[1] += p0.y; af[2] += p1.x; af[3] += p1.y;
                        af[4] += p2.x; af[5] += p2.y; af[6] += p3.x; af[7] += p3.y;
                    }
                }
            }
            float id = invd2[nbase + nl] * INVQ;
            uint4 pk;
            pk.x = (uint)f2bf(af[0] * id) | ((uint)f2bf(af[1] * id) << 16);
            pk.y = (uint)f2bf(af[2] * id) | ((uint)f2bf(af[3] * id) << 16);
            pk.z = (uint)f2bf(af[4] * id) | ((uint)f2bf(af[5] * id) << 16);
            pk.w = (uint)f2bf(af[6] * id) | ((uint)f2bf(af[7] * id) << 16);
            *reinterpret_cast<uint4*>(ub + ((nl * 512 + lane15 * 16) ^ ((nl & 7) << 4))) = pk;
        }
        __syncthreads();

        f32x4 acc[2][2];
#pragma unroll
        for (int rt = 0; rt < 2; ++rt)
#pragma unroll
            for (int ct = 0; ct < 2; ++ct) acc[rt][ct] = (f32x4)(0.0f);
#pragma unroll
        for (int ks = 0; ks < 8; ++ks) {
            short8 b0 = *reinterpret_cast<const short8*>(bp0 + ks * 32);
            short8 b1 = *reinterpret_cast<const short8*>(bp1 + ks * 32);
#pragma unroll
            for (int rt = 0; rt < 2; ++rt) {
                int row = rt * 16 + lane15;
                int byt = (row * 512 + (ks * 32 + g4 * 8) * 2) ^ ((row & 7) << 4);
                short8 af = *reinterpret_cast<const short8*>(ub + byt);
                acc[rt][0] = __builtin_amdgcn_mfma_f32_16x16x32_bf16(af, b0, acc[rt][0], 0, 0, 0);
                acc[rt][1] = __builtin_amdgcn_mfma_f32_16x16x32_bf16(af, b1, acc[rt][1], 0, 0, 0);
            }
        }
#pragma unroll
        for (int ct = 0; ct < 2; ++ct) {
            float bbv = ct == 0 ? bb0 : bb1v;
            float sum = 0.f;
#pragma unroll
            for (int rt = 0; rt < 2; ++rt)
#pragma unroll
                for (int j = 0; j < 4; ++j)
                    sum += fmaxf(acc[rt][ct][j] + bbv, 0.f);
            sum += __shfl_xor(sum, 16);
            sum += __shfl_xor(sum, 32);
            if (g4 == 0) {
                int n = w * 32 + ct * 16 + lane15;
                atomicAdd(&HgP[(t * 8 + (tile & 7)) * HGd + n], sum);
            }
        }
    }
}

// ---------------- GRU input gates ----------------
__global__ __launch_bounds__(768) void k_gi(const float* __restrict__ HgP,
        const float* __restrict__ WihT, const float* __restrict__ b_ih,
        float* __restrict__ gi_all) {
    __shared__ float x[HGd];
    int t = blockIdx.x, g = threadIdx.x;
    if (g < HGd) {
        float s = 0.f;
#pragma unroll
        for (int p = 0; p < 8; ++p) s += HgP[(t * 8 + p) * HGd + g];
        x[g] = s * INVN;
    }
    __syncthreads();
    float a = b_ih[g];
    for (int k = 0; k < HGd; ++k) a += WihT[k * 768 + g] * x[k];
    gi_all[t * 768 + g] = a;
}

// ---------------- single-block GRU + head ----------------
__global__ __launch_bounds__(768, 3) void k_gru1b(const float* __restrict__ gi_all,
        const uint* __restrict__ W_hhq, const float* __restrict__ b_hh,
        const float* __restrict__ Wh1, const float* __restrict__ bh1,
        const float* __restrict__ Wh2, const float* __restrict__ bh2,
        float* __restrict__ out) {
    int tid = threadIdx.x;
    uint wv[128];
#pragma unroll
    for (int i = 0; i < 128; ++i) wv[i] = W_hhq[i * 768 + tid];
    float bh = b_hh[tid];

    __shared__ float hs[HTd];
    __shared__ uint h2s[HTd / 2];
    __shared__ float gh[3 * HTd];
    if (tid < HTd) hs[tid] = 0.0f;
    if (tid < HTd / 2) h2s[tid] = 0u;
    __syncthreads();

    for (int t = 0; t < T_STEPS; ++t) {
        float s = bh;
#pragma unroll
        for (int i = 0; i < 128; i += 4) {
            uint4 hh = *reinterpret_cast<const uint4*>(&h2s[i]);
            s = __builtin_amdgcn_fdot2(u2h(wv[i + 0]), u2h(hh.x), s, false);
            s = __builtin_amdgcn_fdot2(u2h(wv[i + 1]), u2h(hh.y), s, false);
            s = __builtin_amdgcn_fdot2(u2h(wv[i + 2]), u2h(hh.z), s, false);
            s = __builtin_amdgcn_fdot2(u2h(wv[i + 3]), u2h(hh.w), s, false);
        }
        gh[tid] = s;
        __syncthreads();
        if (tid < HTd) {
            float gir = gi_all[t * 768 + tid];
            float giz = gi_all[t * 768 + HTd + tid];
            float gin = gi_all[t * 768 + 2 * HTd + tid];
            float r = 1.0f / (1.0f + expf(-(gir + gh[tid])));
            float z = 1.0f / (1.0f + expf(-(giz + gh[HTd + tid])));
            float n = tanhf(gin + r * gh[2 * HTd + tid]);
            hs[tid] = (1.0f - z) * n + z * hs[tid];
        }
        __syncthreads();
        if (tid < HTd / 2)
            h2s[tid] = packf16(hs[2 * tid], hs[2 * tid + 1]);
        __syncthreads();
    }

    __shared__ float act[64];
    if (tid < 64) {
        float a = bh1[tid];
        const float* wr = Wh1 + tid * HTd;
        for (int k = 0; k < HTd; k += 4) {
            float4 wv4 = *reinterpret_cast<const float4*>(wr + k);
            a += wv4.x * hs[k] + wv4.y * hs[k + 1] + wv4.z * hs[k + 2] + wv4.w * hs[k + 3];
        }
        act[tid] = fmaxf(a, 0.0f);
    }
    __syncthreads();
    if (tid == 0) {
        float y = bh2[0];
        for (int j = 0; j < 64; ++j) y += Wh2[j] * act[j];
        out[0] = y;
    }
}

// ---------------- launch ----------------
extern "C" void kernel_launch(void* const* d_in, const int* in_sizes, int n_in,
                              void* d_out, int out_size, void* d_ws, size_t ws_size,
                              hipStream_t stream) {
    const float* x_seq = (const float*)d_in[0];
    const int*   ei    = (const int*)d_in[1];
    const float* W1l   = (const float*)d_in[2];
    const float* b1l   = (const float*)d_in[3];
    const float* W1r   = (const float*)d_in[4];
    const float* W2l   = (const float*)d_in[5];
    const float* b2l   = (const float*)d_in[6];
    const float* W2r   = (const float*)d_in[7];
    const float* W_ih  = (const float*)d_in[8];
    const float* W_hh  = (const float*)d_in[9];
    const float* b_ih  = (const float*)d_in[10];
    const float* b_hh  = (const float*)d_in[11];
    const float* Wh1   = (const float*)d_in[12];
    const float* bh1   = (const float*)d_in[13];
    const float* Wh2   = (const float*)d_in[14];
    const float* bh2   = (const float*)d_in[15];
    float* out = (float*)d_out;

    char* ws = (char*)d_ws;
    size_t off = 0;
    auto take = [&](size_t nbytes) -> void* {
        void* p = (void*)(ws + off);
        off += (nbytes + 255) & ~(size_t)255;
        return p;
    };
    int*    deg    = (int*)take(N_NODES * 4);
    int*    rp     = (int*)take((N_NODES + 1) * 4);
    int*    cursor = (int*)take(N_NODES * 4);
    int*    csr    = (int*)take(N_EDGES * 4);
    float*  invd   = (float*)take(N_NODES * 4);
    int*    perm   = (int*)take(N_NODES * 4);
    int*    pos    = (int*)take(N_NODES * 4);
    int*    rp2    = (int*)take((N_NODES + 2) * 4);
    int*    rp2p   = (int*)take((N_NODES + 2) * 4);
    int*    csr2p  = (int*)take(480300 * 4);
    float*  invd2  = (float*)take(N_NODES * 4);
    int*    degs2  = (int*)take(N_NODES * 4);
    int*    tb     = (int*)take(520 * 4);
    int*    csr3   = (int*)take(360000 * 4);
    int*    bins   = (int*)take(256 * 4);
    int*    bincur = (int*)take(256 * 4);
    int*    nodeb  = (int*)take(256 * 4);
    int*    edgeb  = (int*)take(256 * 4);
    int*    edgebp = (int*)take(256 * 4);
    ushort* W1T2   = (ushort*)take(128 * 32 * 2);
    ushort* WT2    = (ushort*)take(128 * 256 * 2);
    float*  WihT   = (float*)take(128 * 768 * 4);
    uint*   W_hhq  = (uint*)take(128 * 768 * 4);
    float*  HgP    = (float*)take(T_STEPS * 8 * HGd * 4);
    float*  gi_all = (float*)take(T_STEPS * 768 * 4);
    int*    jobc   = (int*)take(1024 * 4);

    const size_t slice_q = (S_Q8 + 255) & ~(size_t)255;                      // 2.56 MB
    const size_t slice_x = ((size_t)N_NODES * F_IN + 255) & ~(size_t)255;    // 320 KB
    int T_CH = 64;
    while (T_CH > 1 && off + (size_t)T_CH * (slice_q + slice_x) > ws_size)
        T_CH >>= 1;
    uchar1* h1q = (uchar1*)take((size_t)T_CH * slice_q);
    char*   x8  = (char*)take((size_t)T_CH * slice_x);

    k_zero<<<256, 256, 0, stream>>>(deg, HgP, jobc, bins, (uint*)h1q, T_CH);
    k_degree<<<(N_EDGES + 255) / 256, 256, 0, stream>>>(ei, deg);
    k_scan<<<1, 1024, 0, stream>>>(deg, rp, cursor, invd);
    k_fill<<<(N_EDGES + 255) / 256, 256, 0, stream>>>(ei, cursor, csr);
    k_hist<<<(N_NODES + 255) / 256, 256, 0, stream>>>(deg, bins);
    k_binscan<<<1, 256, 0, stream>>>(bins, bincur, nodeb, edgeb, edgebp, rp2p);
    k_perm<<<(N_NODES + 255) / 256, 256, 0, stream>>>(deg, bincur, nodeb, edgeb, edgebp,
                                                      invd, perm, pos, rp2, invd2, degs2, rp2p);
    k_tb<<<1, 512, 0, stream>>>(rp2, tb);
    k_ecopy<<<(N_EDGES + 255) / 256, 256, 0, stream>>>(rp, pos, rp2p, tb, csr, csr3, csr2p);
    k_pad<<<(N_NODES + 255) / 256, 256, 0, stream>>>(rp, pos, rp2p, csr2p);
    {
        int total = 128 * 32 + 128 * 256 + 128 * 768 + 128 * 768;
        k_prepw<<<(total + 255) / 256, 256, 0, stream>>>(W1l, W1r, W2l, W2r, W_ih, W_hh,
                                                         W1T2, WT2, WihT, W_hhq);
    }
    int chunk = 0;
    for (int t0 = 0; t0 < T_STEPS; t0 += T_CH, ++chunk) {
        int C = T_CH;
        int n4 = C * N_NODES * F_IN / 4;
        k_qx<<<(n4 + 255) / 256, 256, 0, stream>>>(
            x_seq + (size_t)t0 * N_NODES * F_IN, (int*)x8, n4);
        k_sage1<<<2048, 256, 0, stream>>>(x8, tb, csr3, degs2, invd2, W1T2, b1l, perm,
                                          h1q, jobc + chunk * 32, C);
        k_sage2<<<2048, 256, 0, stream>>>(h1q, rp2p, csr2p, invd2, WT2, b2l, perm, HgP,
                                          jobc + chunk * 32 + 16, t0, C);
    }
    k_gi<<<T_STEPS, 768, 0, stream>>>(HgP, WihT, b_ih, gi_all);
    k_gru1b<<<1, 768, 0, stream>>>(gi_all, W_hhq, b_hh, Wh1, bh1, Wh2, bh2, out);
}

// Round 20
// 999.465 us; speedup vs baseline: 1.2983x; 1.0873x over previous
//
#include <hip/hip_runtime.h>
#include <hip/hip_bf16.h>

#define N_NODES 20000
#define N_EDGES 320000
#define T_STEPS 64
#define F_IN    16
#define HGd     128
#define HTd     256
#define INVN    (1.0f/20000.0f)
#define NTILES   625
#define S1T      79
#define NG64     313
#define QSCALE   64.0f
#define INVQ     (1.0f/64.0f)
#define QX       32.0f
#define INVQX    (1.0f/32.0f)
#define S_Q8     ((size_t)(N_NODES + 1) * HGd)   // fp8 slice stride incl. zero row

typedef __attribute__((ext_vector_type(8))) short short8;
typedef __attribute__((ext_vector_type(4))) float f32x4;
typedef __attribute__((ext_vector_type(2))) float f32x2;
typedef __attribute__((ext_vector_type(2))) _Float16 half2t;

static __device__ __forceinline__ ushort f2bf(float f) {
    __hip_bfloat16 b = __float2bfloat16(f);
    return *reinterpret_cast<ushort*>(&b);
}
static __device__ __forceinline__ half2t u2h(uint u) {
    half2t h; __builtin_memcpy(&h, &u, 4); return h;
}
static __device__ __forceinline__ uint packf16(float a, float b) {
    auto h = __builtin_amdgcn_cvt_pkrtz(a, b);
    uint u; __builtin_memcpy(&u, &h, 4); return u;
}

// ---------------- init ----------------
__global__ void k_zero(int* __restrict__ deg, float* __restrict__ HgP,
                       int* __restrict__ jobc, int* __restrict__ bins,
                       uint* __restrict__ h1q, int tch) {
    int i = blockIdx.x * blockDim.x + threadIdx.x;
    if (i < N_NODES) deg[i] = 0;
    if (i < T_STEPS * 8 * HGd) HgP[i] = 0.0f;
    if (i < 1024) jobc[i] = 0;
    if (i < 256) bins[i] = 0;
    if (i < tch * 32) {          // zero row N_NODES of each fp8 slice (32 uints)
        int sl = i >> 5, j = i & 31;
        h1q[sl * (S_Q8 / 4) + (size_t)N_NODES * (HGd / 4) + j] = 0u;
    }
}

__global__ void k_degree(const int* __restrict__ ei, int* __restrict__ deg) {
    int e = blockIdx.x * blockDim.x + threadIdx.x;
    if (e < N_EDGES) atomicAdd(&deg[ei[N_EDGES + e]], 1);
}

__global__ __launch_bounds__(1024) void k_scan(const int* __restrict__ deg,
        int* __restrict__ rp, int* __restrict__ cursor, float* __restrict__ invd) {
    __shared__ int sh[1024];
    __shared__ int carry_s;
    int tid = threadIdx.x;
    if (tid == 0) { carry_s = 0; rp[0] = 0; }
    __syncthreads();
    for (int base = 0; base < N_NODES; base += 1024) {
        int i = base + tid;
        int v = (i < N_NODES) ? deg[i] : 0;
        sh[tid] = v;
        __syncthreads();
        for (int off = 1; off < 1024; off <<= 1) {
            int t = (tid >= off) ? sh[tid - off] : 0;
            __syncthreads();
            sh[tid] += t;
            __syncthreads();
        }
        int inc = sh[tid] + carry_s;
        if (i < N_NODES) {
            rp[i + 1] = inc;
            cursor[i] = inc - v;
            invd[i] = (v > 0) ? (1.0f / (float)v) : 0.0f;
        }
        __syncthreads();
        if (tid == 1023) carry_s = inc;
        __syncthreads();
    }
}

__global__ void k_fill(const int* __restrict__ ei, int* __restrict__ cursor,
                       int* __restrict__ csr) {
    int e = blockIdx.x * blockDim.x + threadIdx.x;
    if (e < N_EDGES) {
        int d = ei[N_EDGES + e];
        int p = atomicAdd(&cursor[d], 1);
        csr[p] = ei[e];
    }
}

// ---------------- degree-sort permutation ----------------
__global__ void k_hist(const int* __restrict__ deg, int* __restrict__ bins) {
    int i = blockIdx.x * blockDim.x + threadIdx.x;
    if (i < N_NODES) atomicAdd(&bins[min(deg[i], 255)], 1);
}

__global__ __launch_bounds__(256) void k_binscan(const int* __restrict__ bins,
        int* __restrict__ bincur, int* __restrict__ nodebefore,
        int* __restrict__ edgebefore, int* __restrict__ edgebp, int* __restrict__ rp2p) {
    __shared__ int sh[256], she[256], shp[256];
    int tid = threadIdx.x;
    int b = bins[tid];
    int dp = (tid + 7) & ~7;
    sh[tid] = b;
    she[tid] = b * tid;
    shp[tid] = b * dp;
    __syncthreads();
    for (int off = 1; off < 256; off <<= 1) {
        int v = (tid >= off) ? sh[tid - off] : 0;
        int ve = (tid >= off) ? she[tid - off] : 0;
        int vp = (tid >= off) ? shp[tid - off] : 0;
        __syncthreads();
        sh[tid] += v; she[tid] += ve; shp[tid] += vp;
        __syncthreads();
    }
    bincur[tid] = sh[tid] - b;
    nodebefore[tid] = sh[tid] - b;
    edgebefore[tid] = she[tid] - b * tid;
    edgebp[tid] = shp[tid] - b * dp;
    if (tid == 255) rp2p[N_NODES] = shp[255];
}

__global__ void k_perm(const int* __restrict__ deg, int* __restrict__ bincur,
                       const int* __restrict__ nodebefore, const int* __restrict__ edgebefore,
                       const int* __restrict__ edgebp, const float* __restrict__ invd,
                       int* __restrict__ perm, int* __restrict__ pos,
                       int* __restrict__ rp2, float* __restrict__ invd2,
                       int* __restrict__ degs2, int* __restrict__ rp2p) {
    int i = blockIdx.x * blockDim.x + threadIdx.x;
    if (i < N_NODES) {
        int d = min(deg[i], 255);
        int p = atomicAdd(&bincur[d], 1);
        int rank = p - nodebefore[d];
        perm[p] = i;
        pos[i] = p;
        rp2[p] = edgebefore[d] + rank * d;
        rp2p[p] = edgebp[d] + rank * ((d + 7) & ~7);
        invd2[p] = invd[i];
        degs2[p] = deg[i];
        if (i == 0) rp2[N_NODES] = N_EDGES;
    }
}

// per-64-group transposed edge-list bases (sage1)
__global__ __launch_bounds__(512) void k_tb(const int* __restrict__ rp2, int* __restrict__ tb) {
    __shared__ int sh[512];
    int t = threadIdx.x;
    int md = 0;
    if (t < NG64 && t * 64 < N_NODES) {
        int last = min((t + 1) * 64, N_NODES) - 1;
        md = rp2[last + 1] - rp2[last];
    }
    sh[t] = 64 * md;
    __syncthreads();
    for (int off = 1; off < 512; off <<= 1) {
        int v = (t >= off) ? sh[t - off] : 0;
        __syncthreads();
        sh[t] += v;
        __syncthreads();
    }
    tb[t + 1] = sh[t];
    if (t == 0) tb[0] = 0;
}

// edge-parallel scatter into csr3 (sage1) and csr2p (sage2 padded)
__global__ void k_ecopy(const int* __restrict__ rp, const int* __restrict__ pos,
                        const int* __restrict__ rp2p, const int* __restrict__ tb,
                        const int* __restrict__ csr,
                        int* __restrict__ csr3, int* __restrict__ csr2p) {
    int e = blockIdx.x * blockDim.x + threadIdx.x;
    if (e < N_EDGES) {
        int lo = 0, hi = N_NODES - 1;
#pragma unroll
        for (int it = 0; it < 15; ++it) {
            int mid = (lo + hi + 1) >> 1;
            if (rp[mid] <= e) lo = mid; else hi = mid - 1;
        }
        int i = lo;
        int j = e - rp[i];
        int p = pos[i];
        int v = csr[e];
        csr3[tb[p >> 6] + j * 64 + (p & 63)] = v;
        csr2p[rp2p[p] + j] = v;
    }
}

__global__ void k_pad(const int* __restrict__ rp, const int* __restrict__ pos,
                      const int* __restrict__ rp2p, int* __restrict__ csr2p) {
    int i = blockIdx.x * blockDim.x + threadIdx.x;
    if (i < N_NODES) {
        int d = rp[i + 1] - rp[i];
        int dp = (d + 7) & ~7;
        int o = rp2p[pos[i]];
        for (int k = d; k < dp; ++k) csr2p[o + k] = N_NODES;   // fp8 zero row
    }
}

// ---------------- x_seq fp32 -> fp8 (x32) ----------------
__global__ void k_qx(const float* __restrict__ xs, int* __restrict__ x8, int n4) {
    int i = blockIdx.x * blockDim.x + threadIdx.x;
    if (i < n4) {
        float4 v = reinterpret_cast<const float4*>(xs)[i];
        int q8 = __builtin_amdgcn_cvt_pk_fp8_f32(v.x * QX, v.y * QX, 0, false);
        q8 = __builtin_amdgcn_cvt_pk_fp8_f32(v.z * QX, v.w * QX, q8, true);
        x8[i] = q8;
    }
}

// ---------------- weight prep ----------------
__global__ void k_prepw(const float* __restrict__ W1l, const float* __restrict__ W1r,
                        const float* __restrict__ W2l, const float* __restrict__ W2r,
                        const float* __restrict__ W_ih, const float* __restrict__ W_hh,
                        ushort* __restrict__ W1T2, ushort* __restrict__ WT2,
                        float* __restrict__ WihT, uint* __restrict__ W_hhq) {
    int i = blockIdx.x * blockDim.x + threadIdx.x;
    const int n1 = 128 * 32, n2 = 128 * 256, n3 = 128 * 768, n4 = 128 * 768;
    if (i < n1) {
        int o = i >> 5, k = i & 31;
        float v = (k < 16) ? W1l[o * 16 + k] : W1r[o * 16 + (k - 16)];
        W1T2[i] = f2bf(v);
    } else if (i < n1 + n2) {
        int j = i - n1; int o = j >> 8, k = j & 255;
        float v = (k < 128) ? W2l[o * 128 + k] : W2r[o * 128 + (k - 128)];
        WT2[j] = f2bf(v);
    } else if (i < n1 + n2 + n3) {
        int j = i - n1 - n2; int k = j / 768, g = j % 768;
        WihT[j] = W_ih[g * 128 + k];
    } else if (i < n1 + n2 + n3 + n4) {
        int j = i - n1 - n2 - n3; int dw = j / 768, row = j % 768;
        float a = W_hh[(size_t)row * HTd + 2 * dw];
        float b = W_hh[(size_t)row * HTd + 2 * dw + 1];
        W_hhq[j] = packf16(a, b);
    }
}

// ---------------- SAGE layer 1 (lane-per-node fp8 gather + bf16 MFMA -> fp8 h1) ----------------
__global__ __launch_bounds__(256) void k_sage1(
        const char* __restrict__ x8_, const int* __restrict__ tb,
        const int* __restrict__ csr3, const int* __restrict__ degs2,
        const float* __restrict__ invd2,
        const ushort* __restrict__ W1T2, const float* __restrict__ b1l,
        const int* __restrict__ perm, uchar1* __restrict__ h1q_,
        int* __restrict__ jobc, int C) {
    __shared__ ushort u[256 * 40];
    __shared__ int pnode[256];
    __shared__ int job_s;
    int tid = threadIdx.x;
    int l = tid & 63, w = tid >> 6;
    int lane15 = l & 15, g4 = l >> 4;
    const int xcd = blockIdx.x & 7;
    const int cmin = (C < 8) ? C : 8;
    const int ci = xcd % cmin;
    const int reps = (C >= 8) ? (C >> 3) : 1;
    int* ctr = jobc + ci;
    const int njobs = reps * S1T;

    short8 bfr1[2];
    float bb1[2];
#pragma unroll
    for (int ct = 0; ct < 2; ++ct) {
        int o16 = w * 32 + ct * 16 + lane15;
        bfr1[ct] = *reinterpret_cast<const short8*>(W1T2 + o16 * 32 + g4 * 8);
        bb1[ct] = b1l[o16];
    }

    for (;;) {
        if (tid == 0) job_s = atomicAdd(ctr, 1);
        __syncthreads();
        int job = job_s;
        if (job >= njobs) break;
        int rep = job / S1T;
        int tile = job - rep * S1T;
        int tl = ci + (rep << 3);
        const char* xq = x8_ + (size_t)tl * N_NODES * F_IN;
        char* h1q = (char*)h1q_ + (size_t)tl * S_Q8;
        int p = tile * 256 + tid;
        int node = (p < N_NODES) ? perm[p] : -1;
        pnode[tid] = node;

        float acc[16], rootv[16];
#pragma unroll
        for (int k = 0; k < 16; ++k) { acc[k] = 0.0f; rootv[k] = 0.0f; }
        if (node >= 0) {
            int d = degs2[p];
            const int base = tb[p >> 6] + (p & 63);
            for (int j = 0; j < d; ++j) {
                int idx = csr3[base + j * 64];
                uint4 row = *reinterpret_cast<const uint4*>(xq + (size_t)idx * F_IN);
#pragma unroll
                for (int c = 0; c < 4; ++c) {
                    uint vd = c == 0 ? row.x : c == 1 ? row.y : c == 2 ? row.z : row.w;
                    f32x2 lo = __builtin_amdgcn_cvt_pk_f32_fp8((int)vd, false);
                    f32x2 hi = __builtin_amdgcn_cvt_pk_f32_fp8((int)vd, true);
                    acc[4 * c + 0] += lo.x; acc[4 * c + 1] += lo.y;
                    acc[4 * c + 2] += hi.x; acc[4 * c + 3] += hi.y;
                }
            }
            float id = invd2[p] * INVQX;
#pragma unroll
            for (int k = 0; k < 16; ++k) acc[k] *= id;
            uint4 rv = *reinterpret_cast<const uint4*>(xq + (size_t)node * F_IN);
#pragma unroll
            for (int c = 0; c < 4; ++c) {
                uint vd = c == 0 ? rv.x : c == 1 ? rv.y : c == 2 ? rv.z : rv.w;
                f32x2 lo = __builtin_amdgcn_cvt_pk_f32_fp8((int)vd, false);
                f32x2 hi = __builtin_amdgcn_cvt_pk_f32_fp8((int)vd, true);
                rootv[4 * c + 0] = lo.x * INVQX; rootv[4 * c + 1] = lo.y * INVQX;
                rootv[4 * c + 2] = hi.x * INVQX; rootv[4 * c + 3] = hi.y * INVQX;
            }
        }
        {
            uint dw[16];
#pragma unroll
            for (int i = 0; i < 8; ++i)
                dw[i] = (uint)f2bf(acc[2 * i]) | ((uint)f2bf(acc[2 * i + 1]) << 16);
#pragma unroll
            for (int i = 0; i < 8; ++i)
                dw[8 + i] = (uint)f2bf(rootv[2 * i]) | ((uint)f2bf(rootv[2 * i + 1]) << 16);
            ushort* ur = u + tid * 40;
#pragma unroll
            for (int c = 0; c < 4; ++c)
                *reinterpret_cast<uint4*>(ur + c * 8) =
                    make_uint4(dw[4 * c], dw[4 * c + 1], dw[4 * c + 2], dw[4 * c + 3]);
        }
        __syncthreads();

#pragma unroll 4
        for (int rt = 0; rt < 16; ++rt) {
            int row = rt * 16 + lane15;
            short8 af = *reinterpret_cast<const short8*>(u + row * 40 + g4 * 8);
            f32x4 a0 = __builtin_amdgcn_mfma_f32_16x16x32_bf16(af, bfr1[0], (f32x4)(0.0f), 0, 0, 0);
            f32x4 a1 = __builtin_amdgcn_mfma_f32_16x16x32_bf16(af, bfr1[1], (f32x4)(0.0f), 0, 0, 0);
#pragma unroll
            for (int j = 0; j < 4; ++j) {
                int nl = rt * 16 + g4 * 4 + j;
                int nd = pnode[nl];
                if (nd >= 0) {
                    float v0 = fmaxf(a0[j] + bb1[0], 0.0f) * QSCALE;
                    float v1 = fmaxf(a1[j] + bb1[1], 0.0f) * QSCALE;
                    int q0 = __builtin_amdgcn_cvt_pk_fp8_f32(v0, v0, 0, false);
                    int q1 = __builtin_amdgcn_cvt_pk_fp8_f32(v1, v1, 0, false);
                    h1q[(size_t)nd * HGd + w * 32 + lane15] = (char)q0;
                    h1q[(size_t)nd * HGd + w * 32 + 16 + lane15] = (char)q1;
                }
            }
        }
    }
}

// ---------------- SAGE layer 2 (fp8 padded gather uint4x2-edge + bf16 MFMA) ----------------
__global__ __launch_bounds__(256) void k_sage2(
        const uchar1* __restrict__ h1q_,
        const int* __restrict__ rp2p, const int* __restrict__ csr2p,
        const float* __restrict__ invd2,
        const ushort* __restrict__ WT2, const float* __restrict__ b2l,
        const int* __restrict__ perm, float* __restrict__ HgP,
        int* __restrict__ jobc, int t0, int C) {
    __shared__ uint4 usm4[32 * 512 / 16];
    __shared__ int pnode[32];
    __shared__ int job_s;
    char* ub = (char*)usm4;
    int tid = threadIdx.x;
    int l = tid & 63, w = tid >> 6;
    int lane15 = l & 15, g4 = l >> 4;
    int sub = (l >> 3) & 1, seg8 = l & 7;
    const int xcd = blockIdx.x & 7;
    const int cmin = (C < 8) ? C : 8;
    const int ci = xcd % cmin;
    const int reps = (C >= 8) ? (C >> 3) : 1;
    int* ctr = jobc + ci;
    const int njobs = reps * NTILES;

    short8 bfr[2][8];
    float bb[2];
#pragma unroll
    for (int ct = 0; ct < 2; ++ct) {
        int n = w * 32 + ct * 16 + lane15;
        const ushort* bp = WT2 + n * 256 + g4 * 8;
#pragma unroll
        for (int ks = 0; ks < 8; ++ks)
            bfr[ct][ks] = *reinterpret_cast<const short8*>(bp + ks * 32);
        bb[ct] = b2l[n];
    }

    for (;;) {
        if (tid == 0) job_s = atomicAdd(ctr, 1);
        __syncthreads();
        int job = job_s;
        if (job >= njobs) break;
        int rep = job / NTILES;
        int tile = job - rep * NTILES;
        int tl = ci + ((reps - 1 - rep) << 3);   // freshest slice first
        int t = t0 + tl;
        const char* h1q = (const char*)h1q_ + (size_t)tl * S_Q8;
        int nbase = tile * 32;
        if (tid < 32) pnode[tid] = perm[nbase + tid];
        __syncthreads();

        // root rows (fp8 -> bf16*INVQ)
        {
            int nl = tid >> 3, seg = tid & 7;
            uint4 v = *reinterpret_cast<const uint4*>(h1q + (size_t)pnode[nl] * HGd + seg * 16);
            uint bw[8];
#pragma unroll
            for (int d = 0; d < 4; ++d) {
                uint vd = d == 0 ? v.x : d == 1 ? v.y : d == 2 ? v.z : v.w;
                f32x2 plo = __builtin_amdgcn_cvt_pk_f32_fp8((int)vd, false);
                f32x2 phi = __builtin_amdgcn_cvt_pk_f32_fp8((int)vd, true);
                bw[2 * d]     = (uint)f2bf(plo.x * INVQ) | ((uint)f2bf(plo.y * INVQ) << 16);
                bw[2 * d + 1] = (uint)f2bf(phi.x * INVQ) | ((uint)f2bf(phi.y * INVQ) << 16);
            }
            int base = nl * 512 + 256 + seg * 32;
            int swz = (nl & 7) << 4;
            *reinterpret_cast<uint4*>(ub + (base ^ swz)) =
                make_uint4(bw[0], bw[1], bw[2], bw[3]);
            *reinterpret_cast<uint4*>(ub + ((base + 16) ^ swz)) =
                make_uint4(bw[4], bw[5], bw[6], bw[7]);
        }

        // gather: per 16-lane group, 2 edges in flight (sub), 8 lanes x uint4 per row
#pragma unroll
        for (int g = 0; g < 2; ++g) {
            int nl = w * 8 + g * 4 + g4;
            int sl = rp2p[nbase + nl];
            int dp = rp2p[nbase + nl + 1] - sl;
            const int* cp = csr2p + sl;
            float af[16];
#pragma unroll
            for (int k = 0; k < 16; ++k) af[k] = 0.0f;
            if (dp > 0) {
                int idx[4];
#pragma unroll
                for (int uu = 0; uu < 4; ++uu) idx[uu] = cp[2 * uu + sub];
                for (int j = 0; j < dp; j += 8) {
                    uint4 vv[4];
#pragma unroll
                    for (int uu = 0; uu < 4; ++uu)
                        vv[uu] = *reinterpret_cast<const uint4*>(h1q + (size_t)idx[uu] * HGd + seg8 * 16);
                    cp += 8;
#pragma unroll
                    for (int uu = 0; uu < 4; ++uu) idx[uu] = cp[2 * uu + sub];  // guard reads
#pragma unroll
                    for (int uu = 0; uu < 4; ++uu) {
#pragma unroll
                        for (int c = 0; c < 4; ++c) {
                            uint vd = c == 0 ? vv[uu].x : c == 1 ? vv[uu].y
                                     : c == 2 ? vv[uu].z : vv[uu].w;
                            f32x2 lo = __builtin_amdgcn_cvt_pk_f32_fp8((int)vd, false);
                            f32x2 hi = __builtin_amdgcn_cvt_pk_f32_fp8((int)vd, true);
                            af[4 * c + 0] += lo.x; af[4 * c + 1] += lo.y;
                            af[4 * c + 2] += hi.x; af[4 * c + 3] += hi.y;
                        }
                    }
                }
            }
#pragma unroll
            for (int k = 0; k < 16; ++k) af[k] += __shfl_xor(af[k], 8);
            float id = invd2[nbase + nl] * INVQ;
            if (sub == 0) {
                uint bw[8];
#pragma unroll
                for (int i2 = 0; i2 < 8; ++i2)
                    bw[i2] = (uint)f2bf(af[2 * i2] * id) |
                             ((uint)f2bf(af[2 * i2 + 1] * id) << 16);
                int base = nl * 512 + seg8 * 32;
                int swz = (nl & 7) << 4;
                *reinterpret_cast<uint4*>(ub + (base ^ swz)) =
                    make_uint4(bw[0], bw[1], bw[2], bw[3]);
                *reinterpret_cast<uint4*>(ub + ((base + 16) ^ swz)) =
                    make_uint4(bw[4], bw[5], bw[6], bw[7]);
            }
        }
        __syncthreads();

        f32x4 acc[2][2];
#pragma unroll
        for (int rt = 0; rt < 2; ++rt)
#pragma unroll
            for (int ct = 0; ct < 2; ++ct) acc[rt][ct] = (f32x4)(0.0f);
#pragma unroll
        for (int ks = 0; ks < 8; ++ks) {
#pragma unroll
            for (int rt = 0; rt < 2; ++rt) {
                int row = rt * 16 + lane15;
                int byt = (row * 512 + (ks * 32 + g4 * 8) * 2) ^ ((row & 7) << 4);
                short8 af = *reinterpret_cast<const short8*>(ub + byt);
                acc[rt][0] = __builtin_amdgcn_mfma_f32_16x16x32_bf16(af, bfr[0][ks], acc[rt][0], 0, 0, 0);
                acc[rt][1] = __builtin_amdgcn_mfma_f32_16x16x32_bf16(af, bfr[1][ks], acc[rt][1], 0, 0, 0);
            }
        }
#pragma unroll
        for (int ct = 0; ct < 2; ++ct) {
            float sum = 0.f;
#pragma unroll
            for (int rt = 0; rt < 2; ++rt)
#pragma unroll
                for (int j = 0; j < 4; ++j)
                    sum += fmaxf(acc[rt][ct][j] + bb[ct], 0.f);
            sum += __shfl_xor(sum, 16);
            sum += __shfl_xor(sum, 32);
            if (g4 == 0) {
                int n = w * 32 + ct * 16 + lane15;
                atomicAdd(&HgP[(t * 8 + (tile & 7)) * HGd + n], sum);
            }
        }
    }
}

// ---------------- GRU input gates ----------------
__global__ __launch_bounds__(768) void k_gi(const float* __restrict__ HgP,
        const float* __restrict__ WihT, const float* __restrict__ b_ih,
        float* __restrict__ gi_all) {
    __shared__ float x[HGd];
    int t = blockIdx.x, g = threadIdx.x;
    if (g < HGd) {
        float s = 0.f;
#pragma unroll
        for (int p = 0; p < 8; ++p) s += HgP[(t * 8 + p) * HGd + g];
        x[g] = s * INVN;
    }
    __syncthreads();
    float a = b_ih[g];
    for (int k = 0; k < HGd; ++k) a += WihT[k * 768 + g] * x[k];
    gi_all[t * 768 + g] = a;
}

// ---------------- single-block GRU + head ----------------
__global__ __launch_bounds__(768, 3) void k_gru1b(const float* __restrict__ gi_all,
        const uint* __restrict__ W_hhq, const float* __restrict__ b_hh,
        const float* __restrict__ Wh1, const float* __restrict__ bh1,
        const float* __restrict__ Wh2, const float* __restrict__ bh2,
        float* __restrict__ out) {
    int tid = threadIdx.x;
    uint wv[128];
#pragma unroll
    for (int i = 0; i < 128; ++i) wv[i] = W_hhq[i * 768 + tid];
    float bh = b_hh[tid];

    __shared__ float hs[HTd];
    __shared__ uint h2s[HTd / 2];
    __shared__ float gh[3 * HTd];
    if (tid < HTd) hs[tid] = 0.0f;
    if (tid < HTd / 2) h2s[tid] = 0u;
    __syncthreads();

    for (int t = 0; t < T_STEPS; ++t) {
        float s = bh;
#pragma unroll
        for (int i = 0; i < 128; i += 4) {
            uint4 hh = *reinterpret_cast<const uint4*>(&h2s[i]);
            s = __builtin_amdgcn_fdot2(u2h(wv[i + 0]), u2h(hh.x), s, false);
            s = __builtin_amdgcn_fdot2(u2h(wv[i + 1]), u2h(hh.y), s, false);
            s = __builtin_amdgcn_fdot2(u2h(wv[i + 2]), u2h(hh.z), s, false);
            s = __builtin_amdgcn_fdot2(u2h(wv[i + 3]), u2h(hh.w), s, false);
        }
        gh[tid] = s;
        __syncthreads();
        if (tid < HTd) {
            float gir = gi_all[t * 768 + tid];
            float giz = gi_all[t * 768 + HTd + tid];
            float gin = gi_all[t * 768 + 2 * HTd + tid];
            float r = 1.0f / (1.0f + expf(-(gir + gh[tid])));
            float z = 1.0f / (1.0f + expf(-(giz + gh[HTd + tid])));
            float n = tanhf(gin + r * gh[2 * HTd + tid]);
            hs[tid] = (1.0f - z) * n + z * hs[tid];
        }
        __syncthreads();
        if (tid < HTd / 2)
            h2s[tid] = packf16(hs[2 * tid], hs[2 * tid + 1]);
        __syncthreads();
    }

    __shared__ float act[64];
    if (tid < 64) {
        float a = bh1[tid];
        const float* wr = Wh1 + tid * HTd;
        for (int k = 0; k < HTd; k += 4) {
            float4 wv4 = *reinterpret_cast<const float4*>(wr + k);
            a += wv4.x * hs[k] + wv4.y * hs[k + 1] + wv4.z * hs[k + 2] + wv4.w * hs[k + 3];
        }
        act[tid] = fmaxf(a, 0.0f);
    }
    __syncthreads();
    if (tid == 0) {
        float y = bh2[0];
        for (int j = 0; j < 64; ++j) y += Wh2[j] * act[j];
        out[0] = y;
    }
}

// ---------------- launch ----------------
extern "C" void kernel_launch(void* const* d_in, const int* in_sizes, int n_in,
                              void* d_out, int out_size, void* d_ws, size_t ws_size,
                              hipStream_t stream) {
    const float* x_seq = (const float*)d_in[0];
    const int*   ei    = (const int*)d_in[1];
    const float* W1l   = (const float*)d_in[2];
    const float* b1l   = (const float*)d_in[3];
    const float* W1r   = (const float*)d_in[4];
    const float* W2l   = (const float*)d_in[5];
    const float* b2l   = (const float*)d_in[6];
    const float* W2r   = (const float*)d_in[7];
    const float* W_ih  = (const float*)d_in[8];
    const float* W_hh  = (const float*)d_in[9];
    const float* b_ih  = (const float*)d_in[10];
    const float* b_hh  = (const float*)d_in[11];
    const float* Wh1   = (const float*)d_in[12];
    const float* bh1   = (const float*)d_in[13];
    const float* Wh2   = (const float*)d_in[14];
    const float* bh2   = (const float*)d_in[15];
    float* out = (float*)d_out;

    char* ws = (char*)d_ws;
    size_t off = 0;
    auto take = [&](size_t nbytes) -> void* {
        void* p = (void*)(ws + off);
        off += (nbytes + 255) & ~(size_t)255;
        return p;
    };
    int*    deg    = (int*)take(N_NODES * 4);
    int*    rp     = (int*)take((N_NODES + 1) * 4);
    int*    cursor = (int*)take(N_NODES * 4);
    int*    csr    = (int*)take(N_EDGES * 4);
    float*  invd   = (float*)take(N_NODES * 4);
    int*    perm   = (int*)take(N_NODES * 4);
    int*    pos    = (int*)take(N_NODES * 4);
    int*    rp2    = (int*)take((N_NODES + 2) * 4);
    int*    rp2p   = (int*)take((N_NODES + 2) * 4);
    int*    csr2p  = (int*)take(480300 * 4);
    float*  invd2  = (float*)take(N_NODES * 4);
    int*    degs2  = (int*)take(N_NODES * 4);
    int*    tb     = (int*)take(520 * 4);
    int*    csr3   = (int*)take(360000 * 4);
    int*    bins   = (int*)take(256 * 4);
    int*    bincur = (int*)take(256 * 4);
    int*    nodeb  = (int*)take(256 * 4);
    int*    edgeb  = (int*)take(256 * 4);
    int*    edgebp = (int*)take(256 * 4);
    ushort* W1T2   = (ushort*)take(128 * 32 * 2);
    ushort* WT2    = (ushort*)take(128 * 256 * 2);
    float*  WihT   = (float*)take(128 * 768 * 4);
    uint*   W_hhq  = (uint*)take(128 * 768 * 4);
    float*  HgP    = (float*)take(T_STEPS * 8 * HGd * 4);
    float*  gi_all = (float*)take(T_STEPS * 768 * 4);
    int*    jobc   = (int*)take(1024 * 4);

    const size_t slice_q = (S_Q8 + 255) & ~(size_t)255;                      // 2.56 MB
    const size_t slice_x = ((size_t)N_NODES * F_IN + 255) & ~(size_t)255;    // 320 KB
    int T_CH = 64;
    while (T_CH > 1 && off + (size_t)T_CH * (slice_q + slice_x) > ws_size)
        T_CH >>= 1;
    uchar1* h1q = (uchar1*)take((size_t)T_CH * slice_q);
    char*   x8  = (char*)take((size_t)T_CH * slice_x);

    k_zero<<<256, 256, 0, stream>>>(deg, HgP, jobc, bins, (uint*)h1q, T_CH);
    k_degree<<<(N_EDGES + 255) / 256, 256, 0, stream>>>(ei, deg);
    k_scan<<<1, 1024, 0, stream>>>(deg, rp, cursor, invd);
    k_fill<<<(N_EDGES + 255) / 256, 256, 0, stream>>>(ei, cursor, csr);
    k_hist<<<(N_NODES + 255) / 256, 256, 0, stream>>>(deg, bins);
    k_binscan<<<1, 256, 0, stream>>>(bins, bincur, nodeb, edgeb, edgebp, rp2p);
    k_perm<<<(N_NODES + 255) / 256, 256, 0, stream>>>(deg, bincur, nodeb, edgeb, edgebp,
                                                      invd, perm, pos, rp2, invd2, degs2, rp2p);
    k_tb<<<1, 512, 0, stream>>>(rp2, tb);
    k_ecopy<<<(N_EDGES + 255) / 256, 256, 0, stream>>>(rp, pos, rp2p, tb, csr, csr3, csr2p);
    k_pad<<<(N_NODES + 255) / 256, 256, 0, stream>>>(rp, pos, rp2p, csr2p);
    {
        int total = 128 * 32 + 128 * 256 + 128 * 768 + 128 * 768;
        k_prepw<<<(total + 255) / 256, 256, 0, stream>>>(W1l, W1r, W2l, W2r, W_ih, W_hh,
                                                         W1T2, WT2, WihT, W_hhq);
    }
    int chunk = 0;
    for (int t0 = 0; t0 < T_STEPS; t0 += T_CH, ++chunk) {
        int C = T_CH;
        int n4 = C * N_NODES * F_IN / 4;
        k_qx<<<(n4 + 255) / 256, 256, 0, stream>>>(
            x_seq + (size_t)t0 * N_NODES * F_IN, (int*)x8, n4);
        k_sage1<<<2048, 256, 0, stream>>>(x8, tb, csr3, degs2, invd2, W1T2, b1l, perm,
                                          h1q, jobc + chunk * 32, C);
        k_sage2<<<2048, 256, 0, stream>>>(h1q, rp2p, csr2p, invd2, WT2, b2l, perm, HgP,
                                          jobc + chunk * 32 + 16, t0, C);
    }
    k_gi<<<T_STEPS, 768, 0, stream>>>(HgP, WihT, b_ih, gi_all);
    k_gru1b<<<1, 768, 0, stream>>>(gi_all, W_hhq, b_hh, Wh1, bh1, Wh2, bh2, out);
}

// Round 21
// 999.392 us; speedup vs baseline: 1.2984x; 1.0001x over previous
//
#include <hip/hip_runtime.h>
#include <hip/hip_bf16.h>

#define N_NODES 20000
#define N_EDGES 320000
#define T_STEPS 64
#define F_IN    16
#define HGd     128
#define HTd     256
#define INVN    (1.0f/20000.0f)
#define NTILES   625
#define S1T      79
#define NG64     313
#define QSCALE   64.0f
#define INVQ     (1.0f/64.0f)
#define QX       32.0f
#define INVQX    (1.0f/32.0f)
#define S_Q8     ((size_t)(N_NODES + 1) * HGd)   // fp8 slice stride incl. zero row

typedef __attribute__((ext_vector_type(8))) short short8;
typedef __attribute__((ext_vector_type(4))) float f32x4;
typedef __attribute__((ext_vector_type(2))) float f32x2;
typedef __attribute__((ext_vector_type(2))) _Float16 half2t;

static __device__ __forceinline__ ushort f2bf(float f) {
    __hip_bfloat16 b = __float2bfloat16(f);
    return *reinterpret_cast<ushort*>(&b);
}
static __device__ __forceinline__ half2t u2h(uint u) {
    half2t h; __builtin_memcpy(&h, &u, 4); return h;
}
static __device__ __forceinline__ uint h2u(half2t h) {
    uint u; __builtin_memcpy(&u, &h, 4); return u;
}
static __device__ __forceinline__ uint packf16(float a, float b) {
    auto h = __builtin_amdgcn_cvt_pkrtz(a, b);
    uint u; __builtin_memcpy(&u, &h, 4); return u;
}
static __device__ __forceinline__ ushort f2h(float a) {
    return (ushort)(packf16(a, a) & 0xffffu);
}
// fp8 pair -> packed f16 (scale=1.0 is exponent-0 under either scale semantics)
static __device__ __forceinline__ half2t cvt8h_lo(uint v) {
    auto h = __builtin_amdgcn_cvt_scalef32_pk_f16_fp8(v, 1.0f, false);
    half2t r; __builtin_memcpy(&r, &h, 4); return r;
}
static __device__ __forceinline__ half2t cvt8h_hi(uint v) {
    auto h = __builtin_amdgcn_cvt_scalef32_pk_f16_fp8(v, 1.0f, true);
    half2t r; __builtin_memcpy(&r, &h, 4); return r;
}

// ---------------- init ----------------
__global__ void k_zero(int* __restrict__ deg, float* __restrict__ HgP,
                       int* __restrict__ jobc, int* __restrict__ bins,
                       uint* __restrict__ h1q, int tch) {
    int i = blockIdx.x * blockDim.x + threadIdx.x;
    if (i < N_NODES) deg[i] = 0;
    if (i < T_STEPS * 8 * HGd) HgP[i] = 0.0f;
    if (i < 1024) jobc[i] = 0;
    if (i < 256) bins[i] = 0;
    if (i < tch * 32) {          // zero row N_NODES of each fp8 slice (32 uints)
        int sl = i >> 5, j = i & 31;
        h1q[sl * (S_Q8 / 4) + (size_t)N_NODES * (HGd / 4) + j] = 0u;
    }
}

__global__ void k_degree(const int* __restrict__ ei, int* __restrict__ deg) {
    int e = blockIdx.x * blockDim.x + threadIdx.x;
    if (e < N_EDGES) atomicAdd(&deg[ei[N_EDGES + e]], 1);
}

__global__ __launch_bounds__(1024) void k_scan(const int* __restrict__ deg,
        int* __restrict__ rp, int* __restrict__ cursor, float* __restrict__ invd) {
    __shared__ int sh[1024];
    __shared__ int carry_s;
    int tid = threadIdx.x;
    if (tid == 0) { carry_s = 0; rp[0] = 0; }
    __syncthreads();
    for (int base = 0; base < N_NODES; base += 1024) {
        int i = base + tid;
        int v = (i < N_NODES) ? deg[i] : 0;
        sh[tid] = v;
        __syncthreads();
        for (int off = 1; off < 1024; off <<= 1) {
            int t = (tid >= off) ? sh[tid - off] : 0;
            __syncthreads();
            sh[tid] += t;
            __syncthreads();
        }
        int inc = sh[tid] + carry_s;
        if (i < N_NODES) {
            rp[i + 1] = inc;
            cursor[i] = inc - v;
            invd[i] = (v > 0) ? (1.0f / (float)v) : 0.0f;
        }
        __syncthreads();
        if (tid == 1023) carry_s = inc;
        __syncthreads();
    }
}

__global__ void k_fill(const int* __restrict__ ei, int* __restrict__ cursor,
                       int* __restrict__ csr) {
    int e = blockIdx.x * blockDim.x + threadIdx.x;
    if (e < N_EDGES) {
        int d = ei[N_EDGES + e];
        int p = atomicAdd(&cursor[d], 1);
        csr[p] = ei[e];
    }
}

// ---------------- degree-sort permutation ----------------
__global__ void k_hist(const int* __restrict__ deg, int* __restrict__ bins) {
    int i = blockIdx.x * blockDim.x + threadIdx.x;
    if (i < N_NODES) atomicAdd(&bins[min(deg[i], 255)], 1);
}

__global__ __launch_bounds__(256) void k_binscan(const int* __restrict__ bins,
        int* __restrict__ bincur, int* __restrict__ nodebefore,
        int* __restrict__ edgebefore, int* __restrict__ edgebp, int* __restrict__ rp2p) {
    __shared__ int sh[256], she[256], shp[256];
    int tid = threadIdx.x;
    int b = bins[tid];
    int dp = (tid + 7) & ~7;
    sh[tid] = b;
    she[tid] = b * tid;
    shp[tid] = b * dp;
    __syncthreads();
    for (int off = 1; off < 256; off <<= 1) {
        int v = (tid >= off) ? sh[tid - off] : 0;
        int ve = (tid >= off) ? she[tid - off] : 0;
        int vp = (tid >= off) ? shp[tid - off] : 0;
        __syncthreads();
        sh[tid] += v; she[tid] += ve; shp[tid] += vp;
        __syncthreads();
    }
    bincur[tid] = sh[tid] - b;
    nodebefore[tid] = sh[tid] - b;
    edgebefore[tid] = she[tid] - b * tid;
    edgebp[tid] = shp[tid] - b * dp;
    if (tid == 255) rp2p[N_NODES] = shp[255];
}

__global__ void k_perm(const int* __restrict__ deg, int* __restrict__ bincur,
                       const int* __restrict__ nodebefore, const int* __restrict__ edgebefore,
                       const int* __restrict__ edgebp, const float* __restrict__ invd,
                       int* __restrict__ perm, int* __restrict__ pos,
                       int* __restrict__ rp2, float* __restrict__ invd2,
                       int* __restrict__ degs2, int* __restrict__ rp2p) {
    int i = blockIdx.x * blockDim.x + threadIdx.x;
    if (i < N_NODES) {
        int d = min(deg[i], 255);
        int p = atomicAdd(&bincur[d], 1);
        int rank = p - nodebefore[d];
        perm[p] = i;
        pos[i] = p;
        rp2[p] = edgebefore[d] + rank * d;
        rp2p[p] = edgebp[d] + rank * ((d + 7) & ~7);
        invd2[p] = invd[i];
        degs2[p] = deg[i];
        if (i == 0) rp2[N_NODES] = N_EDGES;
    }
}

// per-64-group transposed edge-list bases (sage1)
__global__ __launch_bounds__(512) void k_tb(const int* __restrict__ rp2, int* __restrict__ tb) {
    __shared__ int sh[512];
    int t = threadIdx.x;
    int md = 0;
    if (t < NG64 && t * 64 < N_NODES) {
        int last = min((t + 1) * 64, N_NODES) - 1;
        md = rp2[last + 1] - rp2[last];
    }
    sh[t] = 64 * md;
    __syncthreads();
    for (int off = 1; off < 512; off <<= 1) {
        int v = (t >= off) ? sh[t - off] : 0;
        __syncthreads();
        sh[t] += v;
        __syncthreads();
    }
    tb[t + 1] = sh[t];
    if (t == 0) tb[0] = 0;
}

// edge-parallel scatter into csr3 (sage1) and csr2p (sage2 padded)
__global__ void k_ecopy(const int* __restrict__ rp, const int* __restrict__ pos,
                        const int* __restrict__ rp2p, const int* __restrict__ tb,
                        const int* __restrict__ csr,
                        int* __restrict__ csr3, int* __restrict__ csr2p) {
    int e = blockIdx.x * blockDim.x + threadIdx.x;
    if (e < N_EDGES) {
        int lo = 0, hi = N_NODES - 1;
#pragma unroll
        for (int it = 0; it < 15; ++it) {
            int mid = (lo + hi + 1) >> 1;
            if (rp[mid] <= e) lo = mid; else hi = mid - 1;
        }
        int i = lo;
        int j = e - rp[i];
        int p = pos[i];
        int v = csr[e];
        csr3[tb[p >> 6] + j * 64 + (p & 63)] = v;
        csr2p[rp2p[p] + j] = v;
    }
}

__global__ void k_pad(const int* __restrict__ rp, const int* __restrict__ pos,
                      const int* __restrict__ rp2p, int* __restrict__ csr2p) {
    int i = blockIdx.x * blockDim.x + threadIdx.x;
    if (i < N_NODES) {
        int d = rp[i + 1] - rp[i];
        int dp = (d + 7) & ~7;
        int o = rp2p[pos[i]];
        for (int k = d; k < dp; ++k) csr2p[o + k] = N_NODES;   // fp8 zero row
    }
}

// ---------------- x_seq fp32 -> fp8 (x32) ----------------
__global__ void k_qx(const float* __restrict__ xs, int* __restrict__ x8, int n4) {
    int i = blockIdx.x * blockDim.x + threadIdx.x;
    if (i < n4) {
        float4 v = reinterpret_cast<const float4*>(xs)[i];
        int q8 = __builtin_amdgcn_cvt_pk_fp8_f32(v.x * QX, v.y * QX, 0, false);
        q8 = __builtin_amdgcn_cvt_pk_fp8_f32(v.z * QX, v.w * QX, q8, true);
        x8[i] = q8;
    }
}

// ---------------- weight prep ----------------
// W1T2 bf16; WT2f f16 *scaled by INVQ* (h1q is in x64 domain); WihT fp32; W_hhq f16
__global__ void k_prepw(const float* __restrict__ W1l, const float* __restrict__ W1r,
                        const float* __restrict__ W2l, const float* __restrict__ W2r,
                        const float* __restrict__ W_ih, const float* __restrict__ W_hh,
                        ushort* __restrict__ W1T2, ushort* __restrict__ WT2f,
                        float* __restrict__ WihT, uint* __restrict__ W_hhq) {
    int i = blockIdx.x * blockDim.x + threadIdx.x;
    const int n1 = 128 * 32, n2 = 128 * 256, n3 = 128 * 768, n4 = 128 * 768;
    if (i < n1) {
        int o = i >> 5, k = i & 31;
        float v = (k < 16) ? W1l[o * 16 + k] : W1r[o * 16 + (k - 16)];
        W1T2[i] = f2bf(v);
    } else if (i < n1 + n2) {
        int j = i - n1; int o = j >> 8, k = j & 255;
        float v = (k < 128) ? W2l[o * 128 + k] : W2r[o * 128 + (k - 128)];
        WT2f[j] = f2h(v * INVQ);
    } else if (i < n1 + n2 + n3) {
        int j = i - n1 - n2; int k = j / 768, g = j % 768;
        WihT[j] = W_ih[g * 128 + k];
    } else if (i < n1 + n2 + n3 + n4) {
        int j = i - n1 - n2 - n3; int dw = j / 768, row = j % 768;
        float a = W_hh[(size_t)row * HTd + 2 * dw];
        float b = W_hh[(size_t)row * HTd + 2 * dw + 1];
        W_hhq[j] = packf16(a, b);
    }
}

// ---------------- SAGE layer 1 (lane-per-node fp8 gather + bf16 MFMA -> fp8 h1) ----------------
__global__ __launch_bounds__(256) void k_sage1(
        const char* __restrict__ x8_, const int* __restrict__ tb,
        const int* __restrict__ csr3, const int* __restrict__ degs2,
        const float* __restrict__ invd2,
        const ushort* __restrict__ W1T2, const float* __restrict__ b1l,
        const int* __restrict__ perm, uchar1* __restrict__ h1q_,
        int* __restrict__ jobc, int C) {
    __shared__ ushort u[256 * 40];
    __shared__ int pnode[256];
    __shared__ int job_s;
    int tid = threadIdx.x;
    int l = tid & 63, w = tid >> 6;
    int lane15 = l & 15, g4 = l >> 4;
    const int xcd = blockIdx.x & 7;
    const int cmin = (C < 8) ? C : 8;
    const int ci = xcd % cmin;
    const int reps = (C >= 8) ? (C >> 3) : 1;
    int* ctr = jobc + ci;
    const int njobs = reps * S1T;

    short8 bfr1[2];
    float bb1[2];
#pragma unroll
    for (int ct = 0; ct < 2; ++ct) {
        int o16 = w * 32 + ct * 16 + lane15;
        bfr1[ct] = *reinterpret_cast<const short8*>(W1T2 + o16 * 32 + g4 * 8);
        bb1[ct] = b1l[o16];
    }

    for (;;) {
        if (tid == 0) job_s = atomicAdd(ctr, 1);
        __syncthreads();
        int job = job_s;
        if (job >= njobs) break;
        int rep = job / S1T;
        int tile = job - rep * S1T;
        int tl = ci + (rep << 3);
        const char* xq = x8_ + (size_t)tl * N_NODES * F_IN;
        char* h1q = (char*)h1q_ + (size_t)tl * S_Q8;
        int p = tile * 256 + tid;
        int node = (p < N_NODES) ? perm[p] : -1;
        pnode[tid] = node;

        float acc[16], rootv[16];
#pragma unroll
        for (int k = 0; k < 16; ++k) { acc[k] = 0.0f; rootv[k] = 0.0f; }
        if (node >= 0) {
            int d = degs2[p];
            const int base = tb[p >> 6] + (p & 63);
            for (int j = 0; j < d; ++j) {
                int idx = csr3[base + j * 64];
                uint4 row = *reinterpret_cast<const uint4*>(xq + (size_t)idx * F_IN);
#pragma unroll
                for (int c = 0; c < 4; ++c) {
                    uint vd = c == 0 ? row.x : c == 1 ? row.y : c == 2 ? row.z : row.w;
                    f32x2 lo = __builtin_amdgcn_cvt_pk_f32_fp8((int)vd, false);
                    f32x2 hi = __builtin_amdgcn_cvt_pk_f32_fp8((int)vd, true);
                    acc[4 * c + 0] += lo.x; acc[4 * c + 1] += lo.y;
                    acc[4 * c + 2] += hi.x; acc[4 * c + 3] += hi.y;
                }
            }
            float id = invd2[p] * INVQX;
#pragma unroll
            for (int k = 0; k < 16; ++k) acc[k] *= id;
            uint4 rv = *reinterpret_cast<const uint4*>(xq + (size_t)node * F_IN);
#pragma unroll
            for (int c = 0; c < 4; ++c) {
                uint vd = c == 0 ? rv.x : c == 1 ? rv.y : c == 2 ? rv.z : rv.w;
                f32x2 lo = __builtin_amdgcn_cvt_pk_f32_fp8((int)vd, false);
                f32x2 hi = __builtin_amdgcn_cvt_pk_f32_fp8((int)vd, true);
                rootv[4 * c + 0] = lo.x * INVQX; rootv[4 * c + 1] = lo.y * INVQX;
                rootv[4 * c + 2] = hi.x * INVQX; rootv[4 * c + 3] = hi.y * INVQX;
            }
        }
        {
            uint dw[16];
#pragma unroll
            for (int i = 0; i < 8; ++i)
                dw[i] = (uint)f2bf(acc[2 * i]) | ((uint)f2bf(acc[2 * i + 1]) << 16);
#pragma unroll
            for (int i = 0; i < 8; ++i)
                dw[8 + i] = (uint)f2bf(rootv[2 * i]) | ((uint)f2bf(rootv[2 * i + 1]) << 16);
            ushort* ur = u + tid * 40;
#pragma unroll
            for (int c = 0; c < 4; ++c)
                *reinterpret_cast<uint4*>(ur + c * 8) =
                    make_uint4(dw[4 * c], dw[4 * c + 1], dw[4 * c + 2], dw[4 * c + 3]);
        }
        __syncthreads();

#pragma unroll 4
        for (int rt = 0; rt < 16; ++rt) {
            int row = rt * 16 + lane15;
            short8 af = *reinterpret_cast<const short8*>(u + row * 40 + g4 * 8);
            f32x4 a0 = __builtin_amdgcn_mfma_f32_16x16x32_bf16(af, bfr1[0], (f32x4)(0.0f), 0, 0, 0);
            f32x4 a1 = __builtin_amdgcn_mfma_f32_16x16x32_bf16(af, bfr1[1], (f32x4)(0.0f), 0, 0, 0);
#pragma unroll
            for (int j = 0; j < 4; ++j) {
                int nl = rt * 16 + g4 * 4 + j;
                int nd = pnode[nl];
                if (nd >= 0) {
                    float v0 = fmaxf(a0[j] + bb1[0], 0.0f) * QSCALE;
                    float v1 = fmaxf(a1[j] + bb1[1], 0.0f) * QSCALE;
                    int q0 = __builtin_amdgcn_cvt_pk_fp8_f32(v0, v0, 0, false);
                    int q1 = __builtin_amdgcn_cvt_pk_fp8_f32(v1, v1, 0, false);
                    h1q[(size_t)nd * HGd + w * 32 + lane15] = (char)q0;
                    h1q[(size_t)nd * HGd + w * 32 + 16 + lane15] = (char)q1;
                }
            }
        }
    }
}

// ---------------- SAGE layer 2 (fp8->f16 decode gather + f16 MFMA) ----------------
__global__ __launch_bounds__(256) void k_sage2(
        const uchar1* __restrict__ h1q_,
        const int* __restrict__ rp2p, const int* __restrict__ csr2p,
        const float* __restrict__ invd2,
        const ushort* __restrict__ WT2f, const float* __restrict__ b2l,
        const int* __restrict__ perm, float* __restrict__ HgP,
        int* __restrict__ jobc, int t0, int C) {
    __shared__ uint4 usm4[32 * 512 / 16];
    __shared__ int pnode[32];
    __shared__ int job_s;
    char* ub = (char*)usm4;
    int tid = threadIdx.x;
    int l = tid & 63, w = tid >> 6;
    int lane15 = l & 15, g4 = l >> 4;
    int sub = (l >> 3) & 1, seg8 = l & 7;
    const int xcd = blockIdx.x & 7;
    const int cmin = (C < 8) ? C : 8;
    const int ci = xcd % cmin;
    const int reps = (C >= 8) ? (C >> 3) : 1;
    int* ctr = jobc + ci;
    const int njobs = reps * NTILES;

    short8 bfr[2][8];
    float bb[2];
#pragma unroll
    for (int ct = 0; ct < 2; ++ct) {
        int n = w * 32 + ct * 16 + lane15;
        const ushort* bp = WT2f + n * 256 + g4 * 8;
#pragma unroll
        for (int ks = 0; ks < 8; ++ks)
            bfr[ct][ks] = *reinterpret_cast<const short8*>(bp + ks * 32);
        bb[ct] = b2l[n];
    }

    for (;;) {
        if (tid == 0) job_s = atomicAdd(ctr, 1);
        __syncthreads();
        int job = job_s;
        if (job >= njobs) break;
        int rep = job / NTILES;
        int tile = job - rep * NTILES;
        int tl = ci + ((reps - 1 - rep) << 3);   // freshest slice first
        int t = t0 + tl;
        const char* h1q = (const char*)h1q_ + (size_t)tl * S_Q8;
        int nbase = tile * 32;
        if (tid < 32) pnode[tid] = perm[nbase + tid];
        __syncthreads();

        // root rows: fp8 -> f16 direct (x64 domain; weights absorb INVQ)
        {
            int nl = tid >> 3, seg = tid & 7;
            uint4 v = *reinterpret_cast<const uint4*>(h1q + (size_t)pnode[nl] * HGd + seg * 16);
            uint bw[8];
#pragma unroll
            for (int d = 0; d < 4; ++d) {
                uint vd = d == 0 ? v.x : d == 1 ? v.y : d == 2 ? v.z : v.w;
                bw[2 * d]     = h2u(cvt8h_lo(vd));
                bw[2 * d + 1] = h2u(cvt8h_hi(vd));
            }
            int base = nl * 512 + 256 + seg * 32;
            int swz = (nl & 7) << 4;
            *reinterpret_cast<uint4*>(ub + (base ^ swz)) =
                make_uint4(bw[0], bw[1], bw[2], bw[3]);
            *reinterpret_cast<uint4*>(ub + ((base + 16) ^ swz)) =
                make_uint4(bw[4], bw[5], bw[6], bw[7]);
        }

        // gather: per 16-lane group, 2 edges in flight (sub), 8 lanes x uint4 per row
        // accumulate packed f16; scale by invd at the end
#pragma unroll
        for (int g = 0; g < 2; ++g) {
            int nl = w * 8 + g * 4 + g4;
            int sl = rp2p[nbase + nl];
            int dp = rp2p[nbase + nl + 1] - sl;
            const int* cp = csr2p + sl;
            half2t a[8];
#pragma unroll
            for (int k = 0; k < 8; ++k) a[k] = (half2t)0;
            if (dp > 0) {
                int idx[4];
#pragma unroll
                for (int uu = 0; uu < 4; ++uu) idx[uu] = cp[2 * uu + sub];
                for (int j = 0; j < dp; j += 8) {
                    uint4 vv[4];
#pragma unroll
                    for (int uu = 0; uu < 4; ++uu)
                        vv[uu] = *reinterpret_cast<const uint4*>(h1q + (size_t)idx[uu] * HGd + seg8 * 16);
                    cp += 8;
#pragma unroll
                    for (int uu = 0; uu < 4; ++uu) idx[uu] = cp[2 * uu + sub];  // guard reads
#pragma unroll
                    for (int uu = 0; uu < 4; ++uu) {
#pragma unroll
                        for (int c = 0; c < 4; ++c) {
                            uint vd = c == 0 ? vv[uu].x : c == 1 ? vv[uu].y
                                     : c == 2 ? vv[uu].z : vv[uu].w;
                            a[2 * c]     += cvt8h_lo(vd);
                            a[2 * c + 1] += cvt8h_hi(vd);
                        }
                    }
                }
            }
            float idf = invd2[nbase + nl];
            _Float16 idh = (_Float16)idf;
            half2t idv; idv[0] = idh; idv[1] = idh;
            uint bw[8];
#pragma unroll
            for (int k = 0; k < 8; ++k) {
                uint av = h2u(a[k]);
                uint ao = __shfl_xor(av, 8);
                half2t s = (u2h(av) + u2h(ao)) * idv;
                bw[k] = h2u(s);
            }
            if (sub == 0) {
                int base = nl * 512 + seg8 * 32;
                int swz = (nl & 7) << 4;
                *reinterpret_cast<uint4*>(ub + (base ^ swz)) =
                    make_uint4(bw[0], bw[1], bw[2], bw[3]);
                *reinterpret_cast<uint4*>(ub + ((base + 16) ^ swz)) =
                    make_uint4(bw[4], bw[5], bw[6], bw[7]);
            }
        }
        __syncthreads();

        f32x4 acc[2][2];
#pragma unroll
        for (int rt = 0; rt < 2; ++rt)
#pragma unroll
            for (int ct = 0; ct < 2; ++ct) acc[rt][ct] = (f32x4)(0.0f);
#pragma unroll
        for (int ks = 0; ks < 8; ++ks) {
#pragma unroll
            for (int rt = 0; rt < 2; ++rt) {
                int row = rt * 16 + lane15;
                int byt = (row * 512 + (ks * 32 + g4 * 8) * 2) ^ ((row & 7) << 4);
                short8 af = *reinterpret_cast<const short8*>(ub + byt);
                acc[rt][0] = __builtin_amdgcn_mfma_f32_16x16x32_f16(af, bfr[0][ks], acc[rt][0], 0, 0, 0);
                acc[rt][1] = __builtin_amdgcn_mfma_f32_16x16x32_f16(af, bfr[1][ks], acc[rt][1], 0, 0, 0);
            }
        }
#pragma unroll
        for (int ct = 0; ct < 2; ++ct) {
            float sum = 0.f;
#pragma unroll
            for (int rt = 0; rt < 2; ++rt)
#pragma unroll
                for (int j = 0; j < 4; ++j)
                    sum += fmaxf(acc[rt][ct][j] + bb[ct], 0.f);
            sum += __shfl_xor(sum, 16);
            sum += __shfl_xor(sum, 32);
            if (g4 == 0) {
                int n = w * 32 + ct * 16 + lane15;
                atomicAdd(&HgP[(t * 8 + (tile & 7)) * HGd + n], sum);
            }
        }
    }
}

// ---------------- GRU input gates ----------------
__global__ __launch_bounds__(768) void k_gi(const float* __restrict__ HgP,
        const float* __restrict__ WihT, const float* __restrict__ b_ih,
        float* __restrict__ gi_all) {
    __shared__ float x[HGd];
    int t = blockIdx.x, g = threadIdx.x;
    if (g < HGd) {
        float s = 0.f;
#pragma unroll
        for (int p = 0; p < 8; ++p) s += HgP[(t * 8 + p) * HGd + g];
        x[g] = s * INVN;
    }
    __syncthreads();
    float a = b_ih[g];
    for (int k = 0; k < HGd; ++k) a += WihT[k * 768 + g] * x[k];
    gi_all[t * 768 + g] = a;
}

// ---------------- single-block GRU + head ----------------
__global__ __launch_bounds__(768, 3) void k_gru1b(const float* __restrict__ gi_all,
        const uint* __restrict__ W_hhq, const float* __restrict__ b_hh,
        const float* __restrict__ Wh1, const float* __restrict__ bh1,
        const float* __restrict__ Wh2, const float* __restrict__ bh2,
        float* __restrict__ out) {
    int tid = threadIdx.x;
    uint wv[128];
#pragma unroll
    for (int i = 0; i < 128; ++i) wv[i] = W_hhq[i * 768 + tid];
    float bh = b_hh[tid];

    __shared__ float hs[HTd];
    __shared__ uint h2s[HTd / 2];
    __shared__ float gh[3 * HTd];
    if (tid < HTd) hs[tid] = 0.0f;
    if (tid < HTd / 2) h2s[tid] = 0u;
    __syncthreads();

    for (int t = 0; t < T_STEPS; ++t) {
        float s = bh;
#pragma unroll
        for (int i = 0; i < 128; i += 4) {
            uint4 hh = *reinterpret_cast<const uint4*>(&h2s[i]);
            s = __builtin_amdgcn_fdot2(u2h(wv[i + 0]), u2h(hh.x), s, false);
            s = __builtin_amdgcn_fdot2(u2h(wv[i + 1]), u2h(hh.y), s, false);
            s = __builtin_amdgcn_fdot2(u2h(wv[i + 2]), u2h(hh.z), s, false);
            s = __builtin_amdgcn_fdot2(u2h(wv[i + 3]), u2h(hh.w), s, false);
        }
        gh[tid] = s;
        __syncthreads();
        if (tid < HTd) {
            float gir = gi_all[t * 768 + tid];
            float giz = gi_all[t * 768 + HTd + tid];
            float gin = gi_all[t * 768 + 2 * HTd + tid];
            float r = 1.0f / (1.0f + expf(-(gir + gh[tid])));
            float z = 1.0f / (1.0f + expf(-(giz + gh[HTd + tid])));
            float n = tanhf(gin + r * gh[2 * HTd + tid]);
            hs[tid] = (1.0f - z) * n + z * hs[tid];
        }
        __syncthreads();
        if (tid < HTd / 2)
            h2s[tid] = packf16(hs[2 * tid], hs[2 * tid + 1]);
        __syncthreads();
    }

    __shared__ float act[64];
    if (tid < 64) {
        float a = bh1[tid];
        const float* wr = Wh1 + tid * HTd;
        for (int k = 0; k < HTd; k += 4) {
            float4 wv4 = *reinterpret_cast<const float4*>(wr + k);
            a += wv4.x * hs[k] + wv4.y * hs[k + 1] + wv4.z * hs[k + 2] + wv4.w * hs[k + 3];
        }
        act[tid] = fmaxf(a, 0.0f);
    }
    __syncthreads();
    if (tid == 0) {
        float y = bh2[0];
        for (int j = 0; j < 64; ++j) y += Wh2[j] * act[j];
        out[0] = y;
    }
}

// ---------------- launch ----------------
extern "C" void kernel_launch(void* const* d_in, const int* in_sizes, int n_in,
                              void* d_out, int out_size, void* d_ws, size_t ws_size,
                              hipStream_t stream) {
    const float* x_seq = (const float*)d_in[0];
    const int*   ei    = (const int*)d_in[1];
    const float* W1l   = (const float*)d_in[2];
    const float* b1l   = (const float*)d_in[3];
    const float* W1r   = (const float*)d_in[4];
    const float* W2l   = (const float*)d_in[5];
    const float* b2l   = (const float*)d_in[6];
    const float* W2r   = (const float*)d_in[7];
    const float* W_ih  = (const float*)d_in[8];
    const float* W_hh  = (const float*)d_in[9];
    const float* b_ih  = (const float*)d_in[10];
    const float* b_hh  = (const float*)d_in[11];
    const float* Wh1   = (const float*)d_in[12];
    const float* bh1   = (const float*)d_in[13];
    const float* Wh2   = (const float*)d_in[14];
    const float* bh2   = (const float*)d_in[15];
    float* out = (float*)d_out;

    char* ws = (char*)d_ws;
    size_t off = 0;
    auto take = [&](size_t nbytes) -> void* {
        void* p = (void*)(ws + off);
        off += (nbytes + 255) & ~(size_t)255;
        return p;
    };
    int*    deg    = (int*)take(N_NODES * 4);
    int*    rp     = (int*)take((N_NODES + 1) * 4);
    int*    cursor = (int*)take(N_NODES * 4);
    int*    csr    = (int*)take(N_EDGES * 4);
    float*  invd   = (float*)take(N_NODES * 4);
    int*    perm   = (int*)take(N_NODES * 4);
    int*    pos    = (int*)take(N_NODES * 4);
    int*    rp2    = (int*)take((N_NODES + 2) * 4);
    int*    rp2p   = (int*)take((N_NODES + 2) * 4);
    int*    csr2p  = (int*)take(480300 * 4);
    float*  invd2  = (float*)take(N_NODES * 4);
    int*    degs2  = (int*)take(N_NODES * 4);
    int*    tb     = (int*)take(520 * 4);
    int*    csr3   = (int*)take(360000 * 4);
    int*    bins   = (int*)take(256 * 4);
    int*    bincur = (int*)take(256 * 4);
    int*    nodeb  = (int*)take(256 * 4);
    int*    edgeb  = (int*)take(256 * 4);
    int*    edgebp = (int*)take(256 * 4);
    ushort* W1T2   = (ushort*)take(128 * 32 * 2);
    ushort* WT2f   = (ushort*)take(128 * 256 * 2);
    float*  WihT   = (float*)take(128 * 768 * 4);
    uint*   W_hhq  = (uint*)take(128 * 768 * 4);
    float*  HgP    = (float*)take(T_STEPS * 8 * HGd * 4);
    float*  gi_all = (float*)take(T_STEPS * 768 * 4);
    int*    jobc   = (int*)take(1024 * 4);

    const size_t slice_q = (S_Q8 + 255) & ~(size_t)255;                      // 2.56 MB
    const size_t slice_x = ((size_t)N_NODES * F_IN + 255) & ~(size_t)255;    // 320 KB
    int T_CH = 64;
    while (T_CH > 1 && off + (size_t)T_CH * (slice_q + slice_x) > ws_size)
        T_CH >>= 1;
    uchar1* h1q = (uchar1*)take((size_t)T_CH * slice_q);
    char*   x8  = (char*)take((size_t)T_CH * slice_x);

    k_zero<<<256, 256, 0, stream>>>(deg, HgP, jobc, bins, (uint*)h1q, T_CH);
    k_degree<<<(N_EDGES + 255) / 256, 256, 0, stream>>>(ei, deg);
    k_scan<<<1, 1024, 0, stream>>>(deg, rp, cursor, invd);
    k_fill<<<(N_EDGES + 255) / 256, 256, 0, stream>>>(ei, cursor, csr);
    k_hist<<<(N_NODES + 255) / 256, 256, 0, stream>>>(deg, bins);
    k_binscan<<<1, 256, 0, stream>>>(bins, bincur, nodeb, edgeb, edgebp, rp2p);
    k_perm<<<(N_NODES + 255) / 256, 256, 0, stream>>>(deg, bincur, nodeb, edgeb, edgebp,
                                                      invd, perm, pos, rp2, invd2, degs2, rp2p);
    k_tb<<<1, 512, 0, stream>>>(rp2, tb);
    k_ecopy<<<(N_EDGES + 255) / 256, 256, 0, stream>>>(rp, pos, rp2p, tb, csr, csr3, csr2p);
    k_pad<<<(N_NODES + 255) / 256, 256, 0, stream>>>(rp, pos, rp2p, csr2p);
    {
        int total = 128 * 32 + 128 * 256 + 128 * 768 + 128 * 768;
        k_prepw<<<(total + 255) / 256, 256, 0, stream>>>(W1l, W1r, W2l, W2r, W_ih, W_hh,
                                                         W1T2, WT2f, WihT, W_hhq);
    }
    int chunk = 0;
    for (int t0 = 0; t0 < T_STEPS; t0 += T_CH, ++chunk) {
        int C = T_CH;
        int n4 = C * N_NODES * F_IN / 4;
        k_qx<<<(n4 + 255) / 256, 256, 0, stream>>>(
            x_seq + (size_t)t0 * N_NODES * F_IN, (int*)x8, n4);
        k_sage1<<<2048, 256, 0, stream>>>(x8, tb, csr3, degs2, invd2, W1T2, b1l, perm,
                                          h1q, jobc + chunk * 32, C);
        k_sage2<<<2048, 256, 0, stream>>>(h1q, rp2p, csr2p, invd2, WT2f, b2l, perm, HgP,
                                          jobc + chunk * 32 + 16, t0, C);
    }
    k_gi<<<T_STEPS, 768, 0, stream>>>(HgP, WihT, b_ih, gi_all);
    k_gru1b<<<1, 768, 0, stream>>>(gi_all, W_hhq, b_hh, Wh1, bh1, Wh2, bh2, out);
}